// Round 1
// baseline (276.770 us; speedup 1.0000x reference)
//
#include <hip/hip_runtime.h>
#include <hip/hip_bf16.h>

// Problem constants
constexpr int N    = 2048;
constexpr int IN   = 256;
constexpr int OUT  = 512;
constexpr int NH   = 8;
constexpr int HD   = 64;   // OUT / NH
constexpr int NCHUNK = 16; // key chunks for attention partials
constexpr int CH = N / NCHUNK; // 128 keys per chunk

// ---------------------------------------------------------------------------
// GEMM: C[N x OUT] = X[N x IN] @ W[IN x OUT] + b   (fp32, 64x64 tile, BK=16)
// ---------------------------------------------------------------------------
__global__ __launch_bounds__(256)
void gemm_bias(const float* __restrict__ X, const float* __restrict__ W,
               const float* __restrict__ b, float* __restrict__ C) {
    __shared__ float xs[16][65];  // xs[k][m]
    __shared__ float ws[16][65];  // ws[k][n]
    const int tid = threadIdx.x;
    const int bx = blockIdx.x;    // n tile (OUT/64 = 8)
    const int by = blockIdx.y;    // m tile (N/64 = 32)
    const int tx = tid & 15, ty = tid >> 4;

    float acc[4][4] = {};

    for (int k0 = 0; k0 < IN; k0 += 16) {
        // load X tile: 64 rows x 16 k, each thread one float4
        {
            const int m  = tid >> 2;
            const int kq = (tid & 3) * 4;
            const float4 v = *(const float4*)(X + (by * 64 + m) * IN + k0 + kq);
            xs[kq + 0][m] = v.x;
            xs[kq + 1][m] = v.y;
            xs[kq + 2][m] = v.z;
            xs[kq + 3][m] = v.w;
        }
        // load W tile: 16 k x 64 n, each thread one float4
        {
            const int k  = tid >> 4;
            const int nq = (tid & 15) * 4;
            const float4 v = *(const float4*)(W + (k0 + k) * OUT + bx * 64 + nq);
            ws[k][nq + 0] = v.x;
            ws[k][nq + 1] = v.y;
            ws[k][nq + 2] = v.z;
            ws[k][nq + 3] = v.w;
        }
        __syncthreads();
        #pragma unroll
        for (int kk = 0; kk < 16; kk++) {
            float a[4], bb[4];
            #pragma unroll
            for (int i = 0; i < 4; i++) a[i]  = xs[kk][ty * 4 + i];
            #pragma unroll
            for (int j = 0; j < 4; j++) bb[j] = ws[kk][tx * 4 + j];
            #pragma unroll
            for (int i = 0; i < 4; i++)
                #pragma unroll
                for (int j = 0; j < 4; j++)
                    acc[i][j] += a[i] * bb[j];
        }
        __syncthreads();
    }

    #pragma unroll
    for (int i = 0; i < 4; i++) {
        const int row = by * 64 + ty * 4 + i;
        const int col = bx * 64 + tx * 4;
        float4 v;
        v.x = acc[i][0] + b[col + 0];
        v.y = acc[i][1] + b[col + 1];
        v.z = acc[i][2] + b[col + 2];
        v.w = acc[i][3] + b[col + 3];
        *(float4*)(C + row * OUT + col) = v;
    }
}

// ---------------------------------------------------------------------------
// prep: Wvo[i][h] = sum_d Wv[i][h*64+d] * Wo[h*64+d];  bvo[h] likewise with bv
// ---------------------------------------------------------------------------
__global__ __launch_bounds__(256)
void prep_wvo(const float* __restrict__ Wv, const float* __restrict__ bv,
              const float* __restrict__ Wo, float* __restrict__ Wvo,
              float* __restrict__ bvo) {
    const int i = threadIdx.x;  // 0..255 (= IN rows)
    #pragma unroll
    for (int h = 0; h < NH; h++) {
        float s = 0.f;
        #pragma unroll
        for (int d = 0; d < HD; d++)
            s += Wv[i * OUT + h * HD + d] * Wo[h * HD + d];
        Wvo[i * NH + h] = s;
    }
    if (i < NH) {
        float s = 0.f;
        #pragma unroll
        for (int d = 0; d < HD; d++)
            s += bv[i * HD + d] * Wo[i * HD + d];
        bvo[i] = s;
    }
}

// ---------------------------------------------------------------------------
// vpm[k][h] = sigmoid(mg_mlp(k)) * ( x[k] @ Wvo[:,h] + bvo[h] )
// ---------------------------------------------------------------------------
__global__ __launch_bounds__(256)
void compute_vpm(const float* __restrict__ x, const float* __restrict__ rel_vel,
                 const float* __restrict__ rel_angle,
                 const float* __restrict__ Wmg1, const float* __restrict__ bmg1,
                 const float* __restrict__ Wmg2, const float* __restrict__ bmg2,
                 const float* __restrict__ Wvo, const float* __restrict__ bvo,
                 float* __restrict__ vpm) {
    const int k = blockIdx.x * 256 + threadIdx.x;
    const float m0 = rel_vel[k], m1 = rel_angle[k];
    float g = bmg2[0];
    #pragma unroll
    for (int j = 0; j < HD; j++) {
        float t = m0 * Wmg1[j] + m1 * Wmg1[HD + j] + bmg1[j];
        t = fmaxf(t, 0.f);
        g += t * Wmg2[j];
    }
    const float mg = 1.f / (1.f + __expf(-g));

    float acc[NH];
    #pragma unroll
    for (int h = 0; h < NH; h++) acc[h] = bvo[h];
    const float* xr = x + k * IN;
    for (int i = 0; i < IN; i++) {
        const float xv = xr[i];
        #pragma unroll
        for (int h = 0; h < NH; h++) acc[h] += xv * Wvo[i * NH + h];
    }
    #pragma unroll
    for (int h = 0; h < NH; h++) vpm[k * NH + h] = mg * acc[h];
}

// ---------------------------------------------------------------------------
// attention partials: one wave = 64 queries x 1 head; loop over a key chunk.
// num[q,h] += exp(s)*vpm[k,h]; den[q,h] += exp(s).  No max-subtraction needed
// (scores are O(1)), ratio identical to softmax.
// ---------------------------------------------------------------------------
__global__ __launch_bounds__(512)
void attn_partial(const float* __restrict__ Q, const float* __restrict__ K,
                  const float* __restrict__ vpm,
                  float* __restrict__ pnum, float* __restrict__ pden) {
    const int q = blockIdx.x * 64 + threadIdx.x;          // query
    const int h = __builtin_amdgcn_readfirstlane((int)threadIdx.y);  // wave-uniform head
    const int c = blockIdx.y;                             // key chunk

    float qreg[HD];
    const float* qp = Q + q * OUT + h * HD;
    #pragma unroll
    for (int d = 0; d < HD; d++) qreg[d] = qp[d];

    float num = 0.f, den = 0.f;
    const int k0 = c * CH;
    for (int k = k0; k < k0 + CH; k++) {
        const float* kp = K + k * OUT + h * HD;   // wave-uniform address -> s_load
        float s = 0.f;
        #pragma unroll
        for (int d = 0; d < HD; d++) s += qreg[d] * kp[d];
        s *= 0.125f;  // 1/sqrt(64)
        const float e = __expf(s);
        den += e;
        num += e * vpm[k * NH + h];               // wave-uniform -> s_load
    }
    pnum[(c * N + q) * NH + h] = num;
    pden[(c * N + q) * NH + h] = den;
}

// ---------------------------------------------------------------------------
// finalize: out[q] = bo + sum_h (sum_c num) / (sum_c den)
// ---------------------------------------------------------------------------
__global__ __launch_bounds__(256)
void finalize(const float* __restrict__ pnum, const float* __restrict__ pden,
              const float* __restrict__ bo, float* __restrict__ out) {
    const int q = blockIdx.x * 256 + threadIdx.x;
    float acc = bo[0];
    #pragma unroll
    for (int h = 0; h < NH; h++) {
        float num = 0.f, den = 0.f;
        for (int ci = 0; ci < NCHUNK; ci++) {
            num += pnum[(ci * N + q) * NH + h];
            den += pden[(ci * N + q) * NH + h];
        }
        acc += num / den;
    }
    out[q] = acc;
}

// ---------------------------------------------------------------------------
extern "C" void kernel_launch(void* const* d_in, const int* in_sizes, int n_in,
                              void* d_out, int out_size, void* d_ws, size_t ws_size,
                              hipStream_t stream) {
    const float* x         = (const float*)d_in[0];
    // d_in[1] = rel_pos (unused: sb cancels in softmax)
    const float* rel_vel   = (const float*)d_in[2];
    const float* rel_angle = (const float*)d_in[3];
    const float* Wq        = (const float*)d_in[4];
    const float* bq        = (const float*)d_in[5];
    const float* Wk        = (const float*)d_in[6];
    const float* bk        = (const float*)d_in[7];
    const float* Wv        = (const float*)d_in[8];
    const float* bv        = (const float*)d_in[9];
    // d_in[10..13] = Wsb1,bsb1,Wsb2,bsb2 (unused)
    const float* Wmg1      = (const float*)d_in[14];
    const float* bmg1      = (const float*)d_in[15];
    const float* Wmg2      = (const float*)d_in[16];
    const float* bmg2      = (const float*)d_in[17];
    const float* Wo        = (const float*)d_in[18];
    const float* bo        = (const float*)d_in[19];
    float* out = (float*)d_out;

    float* ws = (float*)d_ws;
    float* Qm   = ws;                   // N*OUT       = 1048576
    float* Km   = Qm + N * OUT;         // N*OUT       = 1048576
    float* Wvo  = Km + N * OUT;         // IN*NH       = 2048
    float* bvo  = Wvo + IN * NH;        // NH          = 8
    float* vpm  = bvo + NH;             // N*NH        = 16384
    float* pnum = vpm + N * NH;         // NCHUNK*N*NH = 262144
    float* pden = pnum + NCHUNK * N * NH;

    hipLaunchKernelGGL(prep_wvo, dim3(1), dim3(256), 0, stream, Wv, bv, Wo, Wvo, bvo);
    hipLaunchKernelGGL(gemm_bias, dim3(OUT / 64, N / 64), dim3(256), 0, stream, x, Wq, bq, Qm);
    hipLaunchKernelGGL(gemm_bias, dim3(OUT / 64, N / 64), dim3(256), 0, stream, x, Wk, bk, Km);
    hipLaunchKernelGGL(compute_vpm, dim3(N / 256), dim3(256), 0, stream,
                       x, rel_vel, rel_angle, Wmg1, bmg1, Wmg2, bmg2, Wvo, bvo, vpm);
    hipLaunchKernelGGL(attn_partial, dim3(N / 64, NCHUNK), dim3(64, 8), 0, stream,
                       Qm, Km, vpm, pnum, pden);
    hipLaunchKernelGGL(finalize, dim3(N / 256), dim3(256), 0, stream, pnum, pden, bo, out);
}

// Round 2
// 191.320 us; speedup vs baseline: 1.4466x; 1.4466x over previous
//
#include <hip/hip_runtime.h>
#include <hip/hip_bf16.h>

// Problem constants
constexpr int N    = 2048;
constexpr int IN   = 256;
constexpr int OUT  = 512;
constexpr int NH   = 8;
constexpr int HD   = 64;   // OUT / NH
constexpr int NC   = 4;    // key chunks for attention
constexpr int KPB  = N / NC;    // 512 keys per block
constexpr int KT   = KPB / 16;  // 32 key-tiles of 16

typedef __bf16 bf16x8 __attribute__((ext_vector_type(8)));
typedef __bf16 bf16x4 __attribute__((ext_vector_type(4)));
typedef float  f32x4  __attribute__((ext_vector_type(4)));

#if __has_builtin(__builtin_amdgcn_exp2f)
#define EXP2(x) __builtin_amdgcn_exp2f(x)
#else
#define EXP2(x) exp2f(x)
#endif

// Q is pre-scaled by 1/sqrt(64) * log2(e) so attention can use raw exp2.
#define QSCALE (0.125f * 1.44269504088896f)

// ---------------------------------------------------------------------------
// GEMM: C[N x OUT] = (X[N x IN] @ W[IN x OUT] + b) * scale, written as
// bf16 split (hi + lo), hi = bf16(v), lo = bf16(v - hi).  fp32 accumulate.
// ---------------------------------------------------------------------------
__global__ __launch_bounds__(256)
void gemm_bias_split(const float* __restrict__ X, const float* __restrict__ W,
                     const float* __restrict__ b, float scale,
                     __bf16* __restrict__ Chi, __bf16* __restrict__ Clo) {
    __shared__ float xs[16][65];  // xs[k][m]
    __shared__ float ws[16][65];  // ws[k][n]
    const int tid = threadIdx.x;
    const int bx = blockIdx.x;    // n tile (OUT/64 = 8)
    const int by = blockIdx.y;    // m tile (N/64 = 32)
    const int tx = tid & 15, ty = tid >> 4;

    float acc[4][4] = {};

    for (int k0 = 0; k0 < IN; k0 += 16) {
        {
            const int m  = tid >> 2;
            const int kq = (tid & 3) * 4;
            const float4 v = *(const float4*)(X + (by * 64 + m) * IN + k0 + kq);
            xs[kq + 0][m] = v.x;
            xs[kq + 1][m] = v.y;
            xs[kq + 2][m] = v.z;
            xs[kq + 3][m] = v.w;
        }
        {
            const int k  = tid >> 4;
            const int nq = (tid & 15) * 4;
            const float4 v = *(const float4*)(W + (k0 + k) * OUT + bx * 64 + nq);
            ws[k][nq + 0] = v.x;
            ws[k][nq + 1] = v.y;
            ws[k][nq + 2] = v.z;
            ws[k][nq + 3] = v.w;
        }
        __syncthreads();
        #pragma unroll
        for (int kk = 0; kk < 16; kk++) {
            float a[4], bb[4];
            #pragma unroll
            for (int i = 0; i < 4; i++) a[i]  = xs[kk][ty * 4 + i];
            #pragma unroll
            for (int j = 0; j < 4; j++) bb[j] = ws[kk][tx * 4 + j];
            #pragma unroll
            for (int i = 0; i < 4; i++)
                #pragma unroll
                for (int j = 0; j < 4; j++)
                    acc[i][j] += a[i] * bb[j];
        }
        __syncthreads();
    }

    #pragma unroll
    for (int i = 0; i < 4; i++) {
        const int row = by * 64 + ty * 4 + i;
        const int col = bx * 64 + tx * 4;
        bf16x4 hi, lo;
        #pragma unroll
        for (int j = 0; j < 4; j++) {
            const float v = (acc[i][j] + b[col + j]) * scale;
            const __bf16 hv = (__bf16)v;
            hi[j] = hv;
            lo[j] = (__bf16)(v - (float)hv);
        }
        *(bf16x4*)(Chi + (size_t)row * OUT + col) = hi;
        *(bf16x4*)(Clo + (size_t)row * OUT + col) = lo;
    }
}

// ---------------------------------------------------------------------------
// prep: Wvo[i][h] = sum_d Wv[i][h*64+d] * Wo[h*64+d];  bvo[h] likewise w/ bv
// grid 8 x 256, thread = (i = bx*32 + t/8, h = t%8)
// ---------------------------------------------------------------------------
__global__ __launch_bounds__(256)
void prep_wvo(const float* __restrict__ Wv, const float* __restrict__ bv,
              const float* __restrict__ Wo, float* __restrict__ Wvo,
              float* __restrict__ bvo) {
    __shared__ float wo_s[OUT];
    const int tid = threadIdx.x;
    wo_s[tid]       = Wo[tid];
    wo_s[tid + 256] = Wo[tid + 256];
    __syncthreads();

    const int i = blockIdx.x * 32 + (tid >> 3);
    const int h = tid & 7;
    const float* wr = Wv + (size_t)i * OUT + h * HD;
    float s = 0.f;
    #pragma unroll
    for (int d = 0; d < HD; d += 4) {
        const float4 v = *(const float4*)(wr + d);
        s += v.x * wo_s[h * HD + d + 0] + v.y * wo_s[h * HD + d + 1]
           + v.z * wo_s[h * HD + d + 2] + v.w * wo_s[h * HD + d + 3];
    }
    Wvo[i * NH + h] = s;

    if (blockIdx.x == 0 && tid < NH) {
        float sb = 0.f;
        #pragma unroll
        for (int d = 0; d < HD; d++)
            sb += bv[tid * HD + d] * wo_s[tid * HD + d];
        bvo[tid] = sb;
    }
}

// ---------------------------------------------------------------------------
// vpmT[h][k] = sigmoid(mg_mlp(k)) * ( x[k] @ Wvo[:,h] + bvo[h] )
// grid 64 x 256, thread = (k = bx*32 + t/8, h = t%8)
// ---------------------------------------------------------------------------
__global__ __launch_bounds__(256)
void compute_vpm(const float* __restrict__ x, const float* __restrict__ rel_vel,
                 const float* __restrict__ rel_angle,
                 const float* __restrict__ Wmg1, const float* __restrict__ bmg1,
                 const float* __restrict__ Wmg2, const float* __restrict__ bmg2,
                 const float* __restrict__ Wvo, const float* __restrict__ bvo,
                 float* __restrict__ vpmT) {
    __shared__ float wvo_s[IN * NH];  // 8 KB
    const int tid = threadIdx.x;
    #pragma unroll
    for (int i = 0; i < 8; i++) wvo_s[tid + 256 * i] = Wvo[tid + 256 * i];
    __syncthreads();

    const int k = blockIdx.x * 32 + (tid >> 3);
    const int h = tid & 7;

    // motion gate (redundant across h, cheap, wave-uniform weight reads)
    const float m0 = rel_vel[k], m1 = rel_angle[k];
    float g = bmg2[0];
    #pragma unroll
    for (int j = 0; j < HD; j++) {
        float t = m0 * Wmg1[j] + m1 * Wmg1[HD + j] + bmg1[j];
        t = fmaxf(t, 0.f);
        g += t * Wmg2[j];
    }
    const float mg = 1.f / (1.f + __expf(-g));

    const float* xr = x + (size_t)k * IN;
    float a0 = 0.f, a1 = 0.f, a2 = 0.f, a3 = 0.f;
    for (int i = 0; i < IN; i += 4) {
        a0 += xr[i + 0] * wvo_s[(i + 0) * NH + h];
        a1 += xr[i + 1] * wvo_s[(i + 1) * NH + h];
        a2 += xr[i + 2] * wvo_s[(i + 2) * NH + h];
        a3 += xr[i + 3] * wvo_s[(i + 3) * NH + h];
    }
    vpmT[h * N + k] = mg * (a0 + a1 + a2 + a3 + bvo[h]);
}

// ---------------------------------------------------------------------------
// Fused attention partials via bf16x3 MFMA.
// Wave = 32 queries (2 sets of 16) x 1 head; block = 4 waves = 128 q.
// Grid (N/128, NH, NC).  Scores come out pre-scaled by 0.125*log2e (folded
// into Q), so e = exp2(score).  num/den accumulated per (q-row, key-lane),
// butterfly-reduced over the 16 key lanes at the end.
// ---------------------------------------------------------------------------
__global__ __launch_bounds__(256)
void attn_mfma(const __bf16* __restrict__ Qhi, const __bf16* __restrict__ Qlo,
               const __bf16* __restrict__ Khi, const __bf16* __restrict__ Klo,
               const float* __restrict__ vpmT,
               float* __restrict__ pnum, float* __restrict__ pden) {
    const int lane = threadIdx.x;        // 0..63
    const int wave = threadIdx.y;        // 0..3
    const int h = blockIdx.y;
    const int c = blockIdx.z;
    const int qw = blockIdx.x * 128 + wave * 32;
    const int row16 = lane & 15;
    const int quad  = lane >> 4;

    // A fragments: A[m=lane&15][k=quad*8+j]
    bf16x8 ahi[2][2], alo[2][2];
    #pragma unroll
    for (int s = 0; s < 2; s++) {
        const size_t qoff = (size_t)(qw + s * 16 + row16) * OUT + h * HD + quad * 8;
        ahi[s][0] = *(const bf16x8*)(Qhi + qoff);
        ahi[s][1] = *(const bf16x8*)(Qhi + qoff + 32);
        alo[s][0] = *(const bf16x8*)(Qlo + qoff);
        alo[s][1] = *(const bf16x8*)(Qlo + qoff + 32);
    }

    float num_acc[2][4] = {}, den_acc[2][4] = {};
    const int k0 = c * KPB;
    const size_t kbase = (size_t)(k0 + row16) * OUT + h * HD + quad * 8;
    const float* vp = vpmT + h * N + k0 + row16;

    for (int t = 0; t < KT; t++) {
        const size_t koff = kbase + (size_t)t * 16 * OUT;
        const bf16x8 bhi0 = *(const bf16x8*)(Khi + koff);
        const bf16x8 bhi1 = *(const bf16x8*)(Khi + koff + 32);
        const bf16x8 blo0 = *(const bf16x8*)(Klo + koff);
        const bf16x8 blo1 = *(const bf16x8*)(Klo + koff + 32);
        const float vpmv = vp[t * 16];
        #pragma unroll
        for (int s = 0; s < 2; s++) {
            f32x4 acc = {0.f, 0.f, 0.f, 0.f};
            acc = __builtin_amdgcn_mfma_f32_16x16x32_bf16(ahi[s][0], bhi0, acc, 0, 0, 0);
            acc = __builtin_amdgcn_mfma_f32_16x16x32_bf16(ahi[s][1], bhi1, acc, 0, 0, 0);
            acc = __builtin_amdgcn_mfma_f32_16x16x32_bf16(alo[s][0], bhi0, acc, 0, 0, 0);
            acc = __builtin_amdgcn_mfma_f32_16x16x32_bf16(alo[s][1], bhi1, acc, 0, 0, 0);
            acc = __builtin_amdgcn_mfma_f32_16x16x32_bf16(ahi[s][0], blo0, acc, 0, 0, 0);
            acc = __builtin_amdgcn_mfma_f32_16x16x32_bf16(ahi[s][1], blo1, acc, 0, 0, 0);
            #pragma unroll
            for (int r = 0; r < 4; r++) {
                const float e = EXP2(acc[r]);
                num_acc[s][r] += e * vpmv;
                den_acc[s][r] += e;
            }
        }
    }

    // reduce over the 16 key-columns (low 4 lane bits), then store
    #pragma unroll
    for (int s = 0; s < 2; s++) {
        #pragma unroll
        for (int r = 0; r < 4; r++) {
            float n = num_acc[s][r], d = den_acc[s][r];
            #pragma unroll
            for (int m = 1; m < 16; m <<= 1) {
                n += __shfl_xor(n, m, 64);
                d += __shfl_xor(d, m, 64);
            }
            if (row16 == 0) {
                const int q = qw + s * 16 + quad * 4 + r;
                pnum[((size_t)c * N + q) * NH + h] = n;
                pden[((size_t)c * N + q) * NH + h] = d;
            }
        }
    }
}

// ---------------------------------------------------------------------------
// finalize: out[q] = bo + sum_h (sum_c num) / (sum_c den)
// ---------------------------------------------------------------------------
__global__ __launch_bounds__(64)
void finalize(const float* __restrict__ pnum, const float* __restrict__ pden,
              const float* __restrict__ bo, float* __restrict__ out) {
    const int q = blockIdx.x * 64 + threadIdx.x;
    float acc = bo[0];
    #pragma unroll
    for (int h = 0; h < NH; h++) {
        float num = 0.f, den = 0.f;
        #pragma unroll
        for (int ci = 0; ci < NC; ci++) {
            num += pnum[((size_t)ci * N + q) * NH + h];
            den += pden[((size_t)ci * N + q) * NH + h];
        }
        acc += num / den;
    }
    out[q] = acc;
}

// ---------------------------------------------------------------------------
extern "C" void kernel_launch(void* const* d_in, const int* in_sizes, int n_in,
                              void* d_out, int out_size, void* d_ws, size_t ws_size,
                              hipStream_t stream) {
    const float* x         = (const float*)d_in[0];
    // d_in[1] = rel_pos (unused: per-query bias cancels in softmax)
    const float* rel_vel   = (const float*)d_in[2];
    const float* rel_angle = (const float*)d_in[3];
    const float* Wq        = (const float*)d_in[4];
    const float* bq        = (const float*)d_in[5];
    const float* Wk        = (const float*)d_in[6];
    const float* bk        = (const float*)d_in[7];
    const float* Wv        = (const float*)d_in[8];
    const float* bv        = (const float*)d_in[9];
    // d_in[10..13] = Wsb1,bsb1,Wsb2,bsb2 (unused)
    const float* Wmg1      = (const float*)d_in[14];
    const float* bmg1      = (const float*)d_in[15];
    const float* Wmg2      = (const float*)d_in[16];
    const float* bmg2      = (const float*)d_in[17];
    const float* Wo        = (const float*)d_in[18];
    const float* bo        = (const float*)d_in[19];
    float* out = (float*)d_out;

    // workspace layout
    __bf16* Qhi = (__bf16*)d_ws;
    __bf16* Qlo = Qhi + (size_t)N * OUT;
    __bf16* Khi = Qlo + (size_t)N * OUT;
    __bf16* Klo = Khi + (size_t)N * OUT;
    float* fp   = (float*)(Klo + (size_t)N * OUT);
    float* Wvo  = fp;                    // IN*NH   = 2048
    float* bvo  = Wvo + IN * NH;         // NH      = 8
    float* vpmT = bvo + NH;              // NH*N    = 16384
    float* pnum = vpmT + NH * N;         // NC*N*NH = 65536
    float* pden = pnum + NC * N * NH;    // NC*N*NH = 65536

    hipLaunchKernelGGL(prep_wvo, dim3(8), dim3(256), 0, stream, Wv, bv, Wo, Wvo, bvo);
    hipLaunchKernelGGL(gemm_bias_split, dim3(OUT / 64, N / 64), dim3(256), 0, stream,
                       x, Wq, bq, QSCALE, Qhi, Qlo);
    hipLaunchKernelGGL(gemm_bias_split, dim3(OUT / 64, N / 64), dim3(256), 0, stream,
                       x, Wk, bk, 1.0f, Khi, Klo);
    hipLaunchKernelGGL(compute_vpm, dim3(N / 32), dim3(256), 0, stream,
                       x, rel_vel, rel_angle, Wmg1, bmg1, Wmg2, bmg2, Wvo, bvo, vpmT);
    hipLaunchKernelGGL(attn_mfma, dim3(N / 128, NH, NC), dim3(64, 4), 0, stream,
                       Qhi, Qlo, Khi, Klo, vpmT, pnum, pden);
    hipLaunchKernelGGL(finalize, dim3(N / 64), dim3(64), 0, stream, pnum, pden, bo, out);
}

// Round 3
// 186.183 us; speedup vs baseline: 1.4865x; 1.0276x over previous
//
#include <hip/hip_runtime.h>
#include <hip/hip_bf16.h>

// Problem constants
constexpr int N    = 2048;
constexpr int IN   = 256;
constexpr int OUT  = 512;
constexpr int NH   = 8;
constexpr int HD   = 64;      // OUT / NH
constexpr int NQK  = 1024;    // Q|K concatenated columns
constexpr int NC   = 8;       // key chunks for attention
constexpr int KPB  = N / NC;  // 256 keys per block
constexpr int KT   = KPB / 16;// 16 key-tiles of 16

typedef __bf16 bf16x8 __attribute__((ext_vector_type(8)));
typedef __bf16 bf16x4 __attribute__((ext_vector_type(4)));
typedef float  f32x4  __attribute__((ext_vector_type(4)));

#if __has_builtin(__builtin_amdgcn_exp2f)
#define EXP2(x) __builtin_amdgcn_exp2f(x)
#else
#define EXP2(x) exp2f(x)
#endif

// Q is pre-scaled by 1/sqrt(64) * log2(e) so attention uses raw exp2.
#define QSCALE (0.125f * 1.44269504088896f)

// ---------------------------------------------------------------------------
// split_x: Xhi/Xlo bf16 [N][IN] from fp32 x (same layout)
// ---------------------------------------------------------------------------
__global__ __launch_bounds__(256)
void split_x(const float* __restrict__ x, __bf16* __restrict__ Xhi,
             __bf16* __restrict__ Xlo) {
    const int i4 = blockIdx.x * 256 + threadIdx.x;   // 512 blocks
    const float4 v = *(const float4*)(x + (size_t)i4 * 4);
    bf16x4 hi, lo;
    const float vv[4] = {v.x, v.y, v.z, v.w};
    #pragma unroll
    for (int j = 0; j < 4; j++) {
        const __bf16 h = (__bf16)vv[j];
        hi[j] = h;
        lo[j] = (__bf16)(vv[j] - (float)h);
    }
    *(bf16x4*)(Xhi + (size_t)i4 * 4) = hi;
    *(bf16x4*)(Xlo + (size_t)i4 * 4) = lo;
}

// ---------------------------------------------------------------------------
// split_w: WThi/WTlo bf16 [NQK][IN] = transpose of [Wq | Wk]
// grid 256 (k), 256 thr (n'); coalesced reads, scattered 2B writes (L2-held)
// ---------------------------------------------------------------------------
__global__ __launch_bounds__(256)
void split_w(const float* __restrict__ Wq, const float* __restrict__ Wk,
             __bf16* __restrict__ WThi, __bf16* __restrict__ WTlo) {
    const int k = blockIdx.x;
    #pragma unroll
    for (int n0 = 0; n0 < NQK; n0 += 256) {
        const int np = n0 + threadIdx.x;
        const float v = (np < OUT) ? Wq[(size_t)k * OUT + np]
                                   : Wk[(size_t)k * OUT + (np - OUT)];
        const __bf16 h = (__bf16)v;
        WThi[(size_t)np * IN + k] = h;
        WTlo[(size_t)np * IN + k] = (__bf16)(v - (float)h);
    }
}

// ---------------------------------------------------------------------------
// Fused Q|K GEMM via bf16x3 MFMA, no LDS (operands L1/L2-resident).
// C[m][n'] = sum_k X[m][k]*WT[n'][k]; epilogue adds bias, scales Q, splits
// hi/lo, writes head-major [h][m][d].
// grid (NQK/128, N/32), block 256 = 4 waves; wave = 32 m x 32 n'.
// ---------------------------------------------------------------------------
__global__ __launch_bounds__(256)
void gemm_qk(const __bf16* __restrict__ Xhi, const __bf16* __restrict__ Xlo,
             const __bf16* __restrict__ WThi, const __bf16* __restrict__ WTlo,
             const float* __restrict__ bq, const float* __restrict__ bk,
             __bf16* __restrict__ Qhhi, __bf16* __restrict__ Qhlo,
             __bf16* __restrict__ Khhi, __bf16* __restrict__ Khlo) {
    const int lane = threadIdx.x & 63;
    const int wave = threadIdx.x >> 6;
    const int row16 = lane & 15;
    const int quad  = lane >> 4;
    const int mb = blockIdx.y * 32;
    const int nb = blockIdx.x * 128 + wave * 32;

    const size_t ar[2] = {(size_t)(mb + row16) * IN, (size_t)(mb + 16 + row16) * IN};
    const size_t br[2] = {(size_t)(nb + row16) * IN, (size_t)(nb + 16 + row16) * IN};

    f32x4 acc[2][2] = {};
    for (int k0 = 0; k0 < IN; k0 += 32) {
        const int ko = k0 + quad * 8;
        bf16x8 ah[2], al[2], bh[2], bl[2];
        #pragma unroll
        for (int t = 0; t < 2; t++) {
            ah[t] = *(const bf16x8*)(Xhi + ar[t] + ko);
            al[t] = *(const bf16x8*)(Xlo + ar[t] + ko);
            bh[t] = *(const bf16x8*)(WThi + br[t] + ko);
            bl[t] = *(const bf16x8*)(WTlo + br[t] + ko);
        }
        #pragma unroll
        for (int mt = 0; mt < 2; mt++)
            #pragma unroll
            for (int nt = 0; nt < 2; nt++) {
                acc[mt][nt] = __builtin_amdgcn_mfma_f32_16x16x32_bf16(ah[mt], bh[nt], acc[mt][nt], 0, 0, 0);
                acc[mt][nt] = __builtin_amdgcn_mfma_f32_16x16x32_bf16(ah[mt], bl[nt], acc[mt][nt], 0, 0, 0);
                acc[mt][nt] = __builtin_amdgcn_mfma_f32_16x16x32_bf16(al[mt], bh[nt], acc[mt][nt], 0, 0, 0);
            }
    }

    // epilogue: C layout col=lane&15 (n), row=quad*4+r (m)
    const bool isQ = (nb < OUT);  // block-uniform (boundary at bx=4)
    const float scale = isQ ? QSCALE : 1.0f;
    __bf16* dhi = isQ ? Qhhi : Khhi;
    __bf16* dlo = isQ ? Qhlo : Khlo;
    #pragma unroll
    for (int mt = 0; mt < 2; mt++)
        #pragma unroll
        for (int nt = 0; nt < 2; nt++) {
            const int np = nb + nt * 16 + row16;
            const int nq = isQ ? np : np - OUT;
            const float bias = isQ ? bq[nq] : bk[nq];
            const int h = nq >> 6, d = nq & 63;
            #pragma unroll
            for (int r = 0; r < 4; r++) {
                const int m = mb + mt * 16 + quad * 4 + r;
                const float v = (acc[mt][nt][r] + bias) * scale;
                const __bf16 hv = (__bf16)v;
                const size_t off = ((size_t)h * N + m) * HD + d;
                dhi[off] = hv;
                dlo[off] = (__bf16)(v - (float)hv);
            }
        }
}

// ---------------------------------------------------------------------------
// prep: Wvo[i][h] = sum_d Wv[i][h*64+d] * Wo[h*64+d];  bvo[h] likewise w/ bv
// ---------------------------------------------------------------------------
__global__ __launch_bounds__(256)
void prep_wvo(const float* __restrict__ Wv, const float* __restrict__ bv,
              const float* __restrict__ Wo, float* __restrict__ Wvo,
              float* __restrict__ bvo) {
    __shared__ float wo_s[OUT];
    const int tid = threadIdx.x;
    wo_s[tid]       = Wo[tid];
    wo_s[tid + 256] = Wo[tid + 256];
    __syncthreads();

    const int i = blockIdx.x * 32 + (tid >> 3);
    const int h = tid & 7;
    const float* wr = Wv + (size_t)i * OUT + h * HD;
    float s = 0.f;
    #pragma unroll
    for (int d = 0; d < HD; d += 4) {
        const float4 v = *(const float4*)(wr + d);
        s += v.x * wo_s[h * HD + d + 0] + v.y * wo_s[h * HD + d + 1]
           + v.z * wo_s[h * HD + d + 2] + v.w * wo_s[h * HD + d + 3];
    }
    Wvo[i * NH + h] = s;

    if (blockIdx.x == 0 && tid < NH) {
        float sb = 0.f;
        #pragma unroll
        for (int d = 0; d < HD; d++)
            sb += bv[tid * HD + d] * wo_s[tid * HD + d];
        bvo[tid] = sb;
    }
}

// ---------------------------------------------------------------------------
// vpmT[h][k] = sigmoid(mg_mlp(k)) * ( x[k] @ Wvo[:,h] + bvo[h] )
// grid 64 x 256, thread = (k = bx*32 + t/8, h = t%8); float4 x reads
// ---------------------------------------------------------------------------
__global__ __launch_bounds__(256)
void compute_vpm(const float* __restrict__ x, const float* __restrict__ rel_vel,
                 const float* __restrict__ rel_angle,
                 const float* __restrict__ Wmg1, const float* __restrict__ bmg1,
                 const float* __restrict__ Wmg2, const float* __restrict__ bmg2,
                 const float* __restrict__ Wvo, const float* __restrict__ bvo,
                 float* __restrict__ vpmT) {
    __shared__ float wvo_s[IN * NH];  // 8 KB
    const int tid = threadIdx.x;
    #pragma unroll
    for (int i = 0; i < 8; i++) wvo_s[tid + 256 * i] = Wvo[tid + 256 * i];
    __syncthreads();

    const int k = blockIdx.x * 32 + (tid >> 3);
    const int h = tid & 7;

    const float m0 = rel_vel[k], m1 = rel_angle[k];
    float g = bmg2[0];
    #pragma unroll
    for (int j = 0; j < HD; j++) {
        float t = m0 * Wmg1[j] + m1 * Wmg1[HD + j] + bmg1[j];
        t = fmaxf(t, 0.f);
        g += t * Wmg2[j];
    }
    const float mg = 1.f / (1.f + __expf(-g));

    const float4* xr = (const float4*)(x + (size_t)k * IN);
    float a0 = 0.f, a1 = 0.f, a2 = 0.f, a3 = 0.f;
    #pragma unroll 4
    for (int i = 0; i < IN / 4; i++) {
        const float4 v = xr[i];
        a0 += v.x * wvo_s[(i * 4 + 0) * NH + h];
        a1 += v.y * wvo_s[(i * 4 + 1) * NH + h];
        a2 += v.z * wvo_s[(i * 4 + 2) * NH + h];
        a3 += v.w * wvo_s[(i * 4 + 3) * NH + h];
    }
    vpmT[h * N + k] = mg * (a0 + a1 + a2 + a3 + bvo[h]);
}

// ---------------------------------------------------------------------------
// Fused attention partials via bf16x3 MFMA, head-major layout.
// Wave = 32 q x 1 head; block = 4 waves = 128 q; grid (16, NH, NC) = 1024.
// K tile loads are contiguous 2 KB blocks, register double-buffered.
// ---------------------------------------------------------------------------
__global__ __launch_bounds__(256, 4)
void attn_mfma(const __bf16* __restrict__ Qhhi, const __bf16* __restrict__ Qhlo,
               const __bf16* __restrict__ Khhi, const __bf16* __restrict__ Khlo,
               const float* __restrict__ vpmT,
               float* __restrict__ pnum, float* __restrict__ pden) {
    const int lane = threadIdx.x & 63;
    const int wave = threadIdx.x >> 6;
    const int h = blockIdx.y;
    const int c = blockIdx.z;
    const int qw = blockIdx.x * 128 + wave * 32;
    const int row16 = lane & 15;
    const int quad  = lane >> 4;

    // A fragments: A[m=lane&15][k=quad*8+j]
    bf16x8 ahi[2][2], alo[2][2];
    #pragma unroll
    for (int s = 0; s < 2; s++) {
        const size_t qoff = ((size_t)h * N + qw + s * 16 + row16) * HD + quad * 8;
        ahi[s][0] = *(const bf16x8*)(Qhhi + qoff);
        ahi[s][1] = *(const bf16x8*)(Qhhi + qoff + 32);
        alo[s][0] = *(const bf16x8*)(Qhlo + qoff);
        alo[s][1] = *(const bf16x8*)(Qhlo + qoff + 32);
    }

    float num_acc[2][4] = {}, den_acc[2][4] = {};
    const int k0 = c * KPB;
    const size_t kbase = ((size_t)h * N + k0 + row16) * HD + quad * 8;
    const float* vp = vpmT + h * N + k0 + row16;

    // prefetch tile 0
    bf16x8 bh0 = *(const bf16x8*)(Khhi + kbase);
    bf16x8 bh1 = *(const bf16x8*)(Khhi + kbase + 32);
    bf16x8 bl0 = *(const bf16x8*)(Khlo + kbase);
    bf16x8 bl1 = *(const bf16x8*)(Khlo + kbase + 32);
    float vv = vp[0];

    #pragma unroll
    for (int t = 0; t < KT; t++) {
        const int tn = (t + 1 < KT) ? t + 1 : t;
        const size_t ko2 = kbase + (size_t)tn * 16 * HD;
        const bf16x8 nh0 = *(const bf16x8*)(Khhi + ko2);
        const bf16x8 nh1 = *(const bf16x8*)(Khhi + ko2 + 32);
        const bf16x8 nl0 = *(const bf16x8*)(Khlo + ko2);
        const bf16x8 nl1 = *(const bf16x8*)(Khlo + ko2 + 32);
        const float nv = vp[tn * 16];

        #pragma unroll
        for (int s = 0; s < 2; s++) {
            f32x4 acc = {0.f, 0.f, 0.f, 0.f};
            acc = __builtin_amdgcn_mfma_f32_16x16x32_bf16(ahi[s][0], bh0, acc, 0, 0, 0);
            acc = __builtin_amdgcn_mfma_f32_16x16x32_bf16(ahi[s][1], bh1, acc, 0, 0, 0);
            acc = __builtin_amdgcn_mfma_f32_16x16x32_bf16(alo[s][0], bh0, acc, 0, 0, 0);
            acc = __builtin_amdgcn_mfma_f32_16x16x32_bf16(alo[s][1], bh1, acc, 0, 0, 0);
            acc = __builtin_amdgcn_mfma_f32_16x16x32_bf16(ahi[s][0], bl0, acc, 0, 0, 0);
            acc = __builtin_amdgcn_mfma_f32_16x16x32_bf16(ahi[s][1], bl1, acc, 0, 0, 0);
            #pragma unroll
            for (int r = 0; r < 4; r++) {
                const float e = EXP2(acc[r]);
                num_acc[s][r] += e * vv;
                den_acc[s][r] += e;
            }
        }
        bh0 = nh0; bh1 = nh1; bl0 = nl0; bl1 = nl1; vv = nv;
    }

    // reduce over the 16 key-columns (low 4 lane bits), then store
    #pragma unroll
    for (int s = 0; s < 2; s++) {
        #pragma unroll
        for (int r = 0; r < 4; r++) {
            float n = num_acc[s][r], d = den_acc[s][r];
            #pragma unroll
            for (int m = 1; m < 16; m <<= 1) {
                n += __shfl_xor(n, m, 64);
                d += __shfl_xor(d, m, 64);
            }
            if (row16 == 0) {
                const int q = qw + s * 16 + quad * 4 + r;
                pnum[((size_t)c * N + q) * NH + h] = n;
                pden[((size_t)c * N + q) * NH + h] = d;
            }
        }
    }
}

// ---------------------------------------------------------------------------
// finalize: out[q] = bo + sum_h (sum_c num) / (sum_c den)
// ---------------------------------------------------------------------------
__global__ __launch_bounds__(64)
void finalize(const float* __restrict__ pnum, const float* __restrict__ pden,
              const float* __restrict__ bo, float* __restrict__ out) {
    const int q = blockIdx.x * 64 + threadIdx.x;
    float acc = bo[0];
    #pragma unroll
    for (int h = 0; h < NH; h++) {
        float num = 0.f, den = 0.f;
        #pragma unroll
        for (int ci = 0; ci < NC; ci++) {
            num += pnum[((size_t)ci * N + q) * NH + h];
            den += pden[((size_t)ci * N + q) * NH + h];
        }
        acc += num / den;
    }
    out[q] = acc;
}

// ---------------------------------------------------------------------------
extern "C" void kernel_launch(void* const* d_in, const int* in_sizes, int n_in,
                              void* d_out, int out_size, void* d_ws, size_t ws_size,
                              hipStream_t stream) {
    const float* x         = (const float*)d_in[0];
    // d_in[1] = rel_pos (unused: per-query bias cancels in softmax)
    const float* rel_vel   = (const float*)d_in[2];
    const float* rel_angle = (const float*)d_in[3];
    const float* Wq        = (const float*)d_in[4];
    const float* bq        = (const float*)d_in[5];
    const float* Wk        = (const float*)d_in[6];
    const float* bk        = (const float*)d_in[7];
    const float* Wv        = (const float*)d_in[8];
    const float* bv        = (const float*)d_in[9];
    // d_in[10..13] = Wsb1,bsb1,Wsb2,bsb2 (unused)
    const float* Wmg1      = (const float*)d_in[14];
    const float* bmg1      = (const float*)d_in[15];
    const float* Wmg2      = (const float*)d_in[16];
    const float* bmg2      = (const float*)d_in[17];
    const float* Wo        = (const float*)d_in[18];
    const float* bo        = (const float*)d_in[19];
    float* out = (float*)d_out;

    // workspace layout (bf16 first, then fp32)
    __bf16* Xhi  = (__bf16*)d_ws;
    __bf16* Xlo  = Xhi + (size_t)N * IN;        // 524288 elems each
    __bf16* WThi = Xlo + (size_t)N * IN;        // [NQK][IN] = 262144
    __bf16* WTlo = WThi + (size_t)NQK * IN;
    __bf16* Qhhi = WTlo + (size_t)NQK * IN;     // [NH][N][HD] = 1048576
    __bf16* Qhlo = Qhhi + (size_t)NH * N * HD;
    __bf16* Khhi = Qhlo + (size_t)NH * N * HD;
    __bf16* Khlo = Khhi + (size_t)NH * N * HD;
    float* fp    = (float*)(Khlo + (size_t)NH * N * HD);
    float* Wvo   = fp;                          // IN*NH   = 2048
    float* bvo   = Wvo + IN * NH;               // NH
    float* vpmT  = bvo + NH;                    // NH*N    = 16384
    float* pnum  = vpmT + NH * N;               // NC*N*NH = 131072
    float* pden  = pnum + (size_t)NC * N * NH;  // NC*N*NH = 131072

    hipLaunchKernelGGL(split_x, dim3(N * IN / 1024), dim3(256), 0, stream, x, Xhi, Xlo);
    hipLaunchKernelGGL(split_w, dim3(IN), dim3(256), 0, stream, Wq, Wk, WThi, WTlo);
    hipLaunchKernelGGL(prep_wvo, dim3(8), dim3(256), 0, stream, Wv, bv, Wo, Wvo, bvo);
    hipLaunchKernelGGL(gemm_qk, dim3(NQK / 128, N / 32), dim3(256), 0, stream,
                       Xhi, Xlo, WThi, WTlo, bq, bk, Qhhi, Qhlo, Khhi, Khlo);
    hipLaunchKernelGGL(compute_vpm, dim3(N / 32), dim3(256), 0, stream,
                       x, rel_vel, rel_angle, Wmg1, bmg1, Wmg2, bmg2, Wvo, bvo, vpmT);
    hipLaunchKernelGGL(attn_mfma, dim3(N / 128, NH, NC), dim3(256), 0, stream,
                       Qhhi, Qhlo, Khhi, Khlo, vpmT, pnum, pden);
    hipLaunchKernelGGL(finalize, dim3(N / 64), dim3(64), 0, stream, pnum, pden, bo, out);
}

// Round 4
// 181.896 us; speedup vs baseline: 1.5216x; 1.0236x over previous
//
#include <hip/hip_runtime.h>
#include <hip/hip_bf16.h>

// Problem constants
constexpr int N    = 2048;
constexpr int IN   = 256;
constexpr int OUT  = 512;
constexpr int NH   = 8;
constexpr int HD   = 64;      // OUT / NH
constexpr int NQK  = 1024;    // Q|K concatenated columns
constexpr int NC   = 8;       // key chunks for attention
constexpr int KPB  = N / NC;  // 256 keys per block
constexpr int KT   = KPB / 16;// 16 key-tiles of 16

typedef __bf16 bf16x8 __attribute__((ext_vector_type(8)));
typedef __bf16 bf16x4 __attribute__((ext_vector_type(4)));
typedef float  f32x4  __attribute__((ext_vector_type(4)));

#if __has_builtin(__builtin_amdgcn_exp2f)
#define EXP2(x) __builtin_amdgcn_exp2f(x)
#else
#define EXP2(x) exp2f(x)
#endif

// Q is pre-scaled by 1/sqrt(64) * log2(e) so attention uses raw exp2.
#define QSCALE (0.125f * 1.44269504088896f)

// ---------------------------------------------------------------------------
// prep_all: fused split_x (blocks 0..511) + split_w transpose (512..767) +
// prep_wvo (768..775).  One launch instead of three.
// ---------------------------------------------------------------------------
__global__ __launch_bounds__(256)
void prep_all(const float* __restrict__ x,
              const float* __restrict__ Wq, const float* __restrict__ Wk,
              const float* __restrict__ Wv, const float* __restrict__ bv,
              const float* __restrict__ Wo,
              __bf16* __restrict__ Xhi, __bf16* __restrict__ Xlo,
              __bf16* __restrict__ WThi, __bf16* __restrict__ WTlo,
              float* __restrict__ Wvo, float* __restrict__ bvo) {
    __shared__ float smem[32 * 33];   // transpose tile / wo_s
    const int b = blockIdx.x;
    const int tid = threadIdx.x;

    if (b < 512) {
        // ---- split_x: bf16 hi/lo of x, same layout ----
        const size_t i4 = ((size_t)b * 256 + tid) * 4;
        const float4 v = *(const float4*)(x + i4);
        const float vv[4] = {v.x, v.y, v.z, v.w};
        bf16x4 hi, lo;
        #pragma unroll
        for (int j = 0; j < 4; j++) {
            const __bf16 h = (__bf16)vv[j];
            hi[j] = h;
            lo[j] = (__bf16)(vv[j] - (float)h);
        }
        *(bf16x4*)(Xhi + i4) = hi;
        *(bf16x4*)(Xlo + i4) = lo;
    } else if (b < 768) {
        // ---- split_w: WT[n'][k] = [Wq|Wk]^T via LDS 32x32 tile ----
        const int tb = b - 512;
        const int k0 = (tb & 7) * 32;        // k tile
        const int n0 = (tb >> 3) * 32;       // n' tile (never straddles 512)
        const float* W = (n0 < OUT) ? Wq : Wk;
        const int nc = (n0 < OUT) ? n0 : n0 - OUT;
        {
            const int row = tid >> 3;          // k within tile
            const int c4  = (tid & 7) * 4;     // n within tile
            const float4 v = *(const float4*)(W + (size_t)(k0 + row) * OUT + nc + c4);
            smem[row * 33 + c4 + 0] = v.x;
            smem[row * 33 + c4 + 1] = v.y;
            smem[row * 33 + c4 + 2] = v.z;
            smem[row * 33 + c4 + 3] = v.w;
        }
        __syncthreads();
        {
            const int nrow = tid >> 3;         // n within tile
            const int k4   = (tid & 7) * 4;    // k within tile
            bf16x4 hi, lo;
            #pragma unroll
            for (int j = 0; j < 4; j++) {
                const float v = smem[(k4 + j) * 33 + nrow];
                const __bf16 h = (__bf16)v;
                hi[j] = h;
                lo[j] = (__bf16)(v - (float)h);
            }
            const size_t off = (size_t)(n0 + nrow) * IN + k0 + k4;
            *(bf16x4*)(WThi + off) = hi;
            *(bf16x4*)(WTlo + off) = lo;
        }
    } else {
        // ---- prep_wvo ----
        float* wo_s = smem;
        wo_s[tid]       = Wo[tid];
        wo_s[tid + 256] = Wo[tid + 256];
        __syncthreads();
        const int i = (b - 768) * 32 + (tid >> 3);
        const int h = tid & 7;
        const float* wr = Wv + (size_t)i * OUT + h * HD;
        float s = 0.f;
        #pragma unroll
        for (int d = 0; d < HD; d += 4) {
            const float4 v = *(const float4*)(wr + d);
            s += v.x * wo_s[h * HD + d + 0] + v.y * wo_s[h * HD + d + 1]
               + v.z * wo_s[h * HD + d + 2] + v.w * wo_s[h * HD + d + 3];
        }
        Wvo[i * NH + h] = s;
        if (b == 768 && tid < NH) {
            float sb = 0.f;
            #pragma unroll
            for (int d = 0; d < HD; d++)
                sb += bv[tid * HD + d] * wo_s[tid * HD + d];
            bvo[tid] = sb;
        }
    }
}

// ---------------------------------------------------------------------------
// Fused Q|K GEMM via bf16x3 MFMA, no LDS in main loop.  Epilogue stages the
// 32m x 128n hi/lo tiles in LDS and writes full 128B lines head-major
// [h][m][d].  grid (NQK/128, N/32), block 256 = 4 waves (wave = 32m x 32n').
// ---------------------------------------------------------------------------
__global__ __launch_bounds__(256)
void gemm_qk(const __bf16* __restrict__ Xhi, const __bf16* __restrict__ Xlo,
             const __bf16* __restrict__ WThi, const __bf16* __restrict__ WTlo,
             const float* __restrict__ bq, const float* __restrict__ bk,
             __bf16* __restrict__ Qhhi, __bf16* __restrict__ Qhlo,
             __bf16* __restrict__ Khhi, __bf16* __restrict__ Khlo) {
    __shared__ __bf16 stage[2][32 * 132];  // [hi/lo][m][n], pad 132
    const int tid  = threadIdx.x;
    const int lane = tid & 63;
    const int wave = tid >> 6;
    const int row16 = lane & 15;
    const int quad  = lane >> 4;
    const int mb = blockIdx.y * 32;
    const int nb0 = blockIdx.x * 128;
    const int nb = nb0 + wave * 32;

    const size_t ar[2] = {(size_t)(mb + row16) * IN, (size_t)(mb + 16 + row16) * IN};
    const size_t br[2] = {(size_t)(nb + row16) * IN, (size_t)(nb + 16 + row16) * IN};

    f32x4 acc[2][2] = {};
    for (int k0 = 0; k0 < IN; k0 += 32) {
        const int ko = k0 + quad * 8;
        bf16x8 ah[2], al[2], bh[2], bl[2];
        #pragma unroll
        for (int t = 0; t < 2; t++) {
            ah[t] = *(const bf16x8*)(Xhi + ar[t] + ko);
            al[t] = *(const bf16x8*)(Xlo + ar[t] + ko);
            bh[t] = *(const bf16x8*)(WThi + br[t] + ko);
            bl[t] = *(const bf16x8*)(WTlo + br[t] + ko);
        }
        #pragma unroll
        for (int mt = 0; mt < 2; mt++)
            #pragma unroll
            for (int nt = 0; nt < 2; nt++) {
                acc[mt][nt] = __builtin_amdgcn_mfma_f32_16x16x32_bf16(ah[mt], bh[nt], acc[mt][nt], 0, 0, 0);
                acc[mt][nt] = __builtin_amdgcn_mfma_f32_16x16x32_bf16(ah[mt], bl[nt], acc[mt][nt], 0, 0, 0);
                acc[mt][nt] = __builtin_amdgcn_mfma_f32_16x16x32_bf16(al[mt], bh[nt], acc[mt][nt], 0, 0, 0);
            }
    }

    // stage into LDS (C layout: col n = lane&15, row m = quad*4+r)
    const bool isQ = (nb0 < OUT);   // block-uniform (bx 0-3 Q, 4-7 K)
    const float scale = isQ ? QSCALE : 1.0f;
    #pragma unroll
    for (int mt = 0; mt < 2; mt++)
        #pragma unroll
        for (int nt = 0; nt < 2; nt++) {
            const int nl = wave * 32 + nt * 16 + row16;   // 0..127
            const int np = nb0 + nl;
            const int nq = isQ ? np : np - OUT;
            const float bias = isQ ? bq[nq] : bk[nq];
            #pragma unroll
            for (int r = 0; r < 4; r++) {
                const int ml = mt * 16 + quad * 4 + r;    // 0..31
                const float v = (acc[mt][nt][r] + bias) * scale;
                const __bf16 hv = (__bf16)v;
                stage[0][ml * 132 + nl] = hv;
                stage[1][ml * 132 + nl] = (__bf16)(v - (float)hv);
            }
        }
    __syncthreads();

    // write out full lines: 64 rows (2 heads x 32 m) x 128B each
    __bf16* dhi = isQ ? Qhhi : Khhi;
    __bf16* dlo = isQ ? Qhlo : Khlo;
    const int r2   = tid >> 2;         // 0..63
    const int cidx = tid & 3;          // 32B chunk
    const int hl   = r2 >> 5;          // head within block
    const int m    = r2 & 31;
    const int nqh  = (isQ ? nb0 : nb0 - OUT) + hl * 64;
    const int h    = nqh >> 6;
    const size_t goff = ((size_t)h * N + mb + m) * HD + cidx * 16;
    const int soff = m * 132 + hl * 64 + cidx * 16;
    *(bf16x8*)(dhi + goff) = *(const bf16x8*)(&stage[0][soff]);
    *(bf16x8*)(dhi + goff + 8) = *(const bf16x8*)(&stage[0][soff + 8]);
    *(bf16x8*)(dlo + goff) = *(const bf16x8*)(&stage[1][soff]);
    *(bf16x8*)(dlo + goff + 8) = *(const bf16x8*)(&stage[1][soff + 8]);
}

// ---------------------------------------------------------------------------
// vpmT[h][k] = sigmoid(mg_mlp(k)) * ( x[k] @ Wvo[:,h] + bvo[h] )
// ---------------------------------------------------------------------------
__global__ __launch_bounds__(256)
void compute_vpm(const float* __restrict__ x, const float* __restrict__ rel_vel,
                 const float* __restrict__ rel_angle,
                 const float* __restrict__ Wmg1, const float* __restrict__ bmg1,
                 const float* __restrict__ Wmg2, const float* __restrict__ bmg2,
                 const float* __restrict__ Wvo, const float* __restrict__ bvo,
                 float* __restrict__ vpmT) {
    __shared__ float wvo_s[IN * NH];  // 8 KB
    const int tid = threadIdx.x;
    #pragma unroll
    for (int i = 0; i < 8; i++) wvo_s[tid + 256 * i] = Wvo[tid + 256 * i];
    __syncthreads();

    const int k = blockIdx.x * 32 + (tid >> 3);
    const int h = tid & 7;

    const float m0 = rel_vel[k], m1 = rel_angle[k];
    float g = bmg2[0];
    #pragma unroll
    for (int j = 0; j < HD; j++) {
        float t = m0 * Wmg1[j] + m1 * Wmg1[HD + j] + bmg1[j];
        t = fmaxf(t, 0.f);
        g += t * Wmg2[j];
    }
    const float mg = 1.f / (1.f + __expf(-g));

    const float4* xr = (const float4*)(x + (size_t)k * IN);
    float a0 = 0.f, a1 = 0.f, a2 = 0.f, a3 = 0.f;
    #pragma unroll 4
    for (int i = 0; i < IN / 4; i++) {
        const float4 v = xr[i];
        a0 += v.x * wvo_s[(i * 4 + 0) * NH + h];
        a1 += v.y * wvo_s[(i * 4 + 1) * NH + h];
        a2 += v.z * wvo_s[(i * 4 + 2) * NH + h];
        a3 += v.w * wvo_s[(i * 4 + 3) * NH + h];
    }
    vpmT[h * N + k] = mg * (a0 + a1 + a2 + a3 + bvo[h]);
}

// ---------------------------------------------------------------------------
// Fused attention partials via bf16x3 MFMA, head-major layout.
// 1D grid of 1024 blocks, decode h = b%8 so (with round-robin block->XCD
// placement) each XCD touches exactly one head: per-XCD L2 working set =
// K[h]+Q[h]+vpm[h] ~= 1 MB << 4 MiB.
// ---------------------------------------------------------------------------
__global__ __launch_bounds__(256, 4)
void attn_mfma(const __bf16* __restrict__ Qhhi, const __bf16* __restrict__ Qhlo,
               const __bf16* __restrict__ Khhi, const __bf16* __restrict__ Khlo,
               const float* __restrict__ vpmT,
               float* __restrict__ pnum, float* __restrict__ pden) {
    const int b = blockIdx.x;
    const int h = b & 7;              // XCD-pinned head
    const int rem = b >> 3;
    const int xq = rem & 15;          // q-block
    const int c = rem >> 4;           // key chunk
    const int lane = threadIdx.x & 63;
    const int wave = threadIdx.x >> 6;
    const int qw = xq * 128 + wave * 32;
    const int row16 = lane & 15;
    const int quad  = lane >> 4;

    // A fragments: A[m=lane&15][k=quad*8+j]
    bf16x8 ahi[2][2], alo[2][2];
    #pragma unroll
    for (int s = 0; s < 2; s++) {
        const size_t qoff = ((size_t)h * N + qw + s * 16 + row16) * HD + quad * 8;
        ahi[s][0] = *(const bf16x8*)(Qhhi + qoff);
        ahi[s][1] = *(const bf16x8*)(Qhhi + qoff + 32);
        alo[s][0] = *(const bf16x8*)(Qhlo + qoff);
        alo[s][1] = *(const bf16x8*)(Qhlo + qoff + 32);
    }

    float num_acc[2][4] = {}, den_acc[2][4] = {};
    const int k0 = c * KPB;
    const size_t kbase = ((size_t)h * N + k0 + row16) * HD + quad * 8;
    const float* vp = vpmT + h * N + k0 + row16;

    // prefetch tile 0
    bf16x8 bh0 = *(const bf16x8*)(Khhi + kbase);
    bf16x8 bh1 = *(const bf16x8*)(Khhi + kbase + 32);
    bf16x8 bl0 = *(const bf16x8*)(Khlo + kbase);
    bf16x8 bl1 = *(const bf16x8*)(Khlo + kbase + 32);
    float vv = vp[0];

    #pragma unroll
    for (int t = 0; t < KT; t++) {
        const int tn = (t + 1 < KT) ? t + 1 : t;
        const size_t ko2 = kbase + (size_t)tn * 16 * HD;
        const bf16x8 nh0 = *(const bf16x8*)(Khhi + ko2);
        const bf16x8 nh1 = *(const bf16x8*)(Khhi + ko2 + 32);
        const bf16x8 nl0 = *(const bf16x8*)(Khlo + ko2);
        const bf16x8 nl1 = *(const bf16x8*)(Khlo + ko2 + 32);
        const float nv = vp[tn * 16];

        #pragma unroll
        for (int s = 0; s < 2; s++) {
            f32x4 acc = {0.f, 0.f, 0.f, 0.f};
            acc = __builtin_amdgcn_mfma_f32_16x16x32_bf16(ahi[s][0], bh0, acc, 0, 0, 0);
            acc = __builtin_amdgcn_mfma_f32_16x16x32_bf16(ahi[s][1], bh1, acc, 0, 0, 0);
            acc = __builtin_amdgcn_mfma_f32_16x16x32_bf16(alo[s][0], bh0, acc, 0, 0, 0);
            acc = __builtin_amdgcn_mfma_f32_16x16x32_bf16(alo[s][1], bh1, acc, 0, 0, 0);
            acc = __builtin_amdgcn_mfma_f32_16x16x32_bf16(ahi[s][0], bl0, acc, 0, 0, 0);
            acc = __builtin_amdgcn_mfma_f32_16x16x32_bf16(ahi[s][1], bl1, acc, 0, 0, 0);
            #pragma unroll
            for (int r = 0; r < 4; r++) {
                const float e = EXP2(acc[r]);
                num_acc[s][r] += e * vv;
                den_acc[s][r] += e;
            }
        }
        bh0 = nh0; bh1 = nh1; bl0 = nl0; bl1 = nl1; vv = nv;
    }

    // reduce over the 16 key-columns (low 4 lane bits), then store
    #pragma unroll
    for (int s = 0; s < 2; s++) {
        #pragma unroll
        for (int r = 0; r < 4; r++) {
            float n = num_acc[s][r], d = den_acc[s][r];
            #pragma unroll
            for (int m = 1; m < 16; m <<= 1) {
                n += __shfl_xor(n, m, 64);
                d += __shfl_xor(d, m, 64);
            }
            if (row16 == 0) {
                const int q = qw + s * 16 + quad * 4 + r;
                pnum[((size_t)c * N + q) * NH + h] = n;
                pden[((size_t)c * N + q) * NH + h] = d;
            }
        }
    }
}

// ---------------------------------------------------------------------------
// finalize: out[q] = bo + sum_h (sum_c num) / (sum_c den)
// ---------------------------------------------------------------------------
__global__ __launch_bounds__(64)
void finalize(const float* __restrict__ pnum, const float* __restrict__ pden,
              const float* __restrict__ bo, float* __restrict__ out) {
    const int q = blockIdx.x * 64 + threadIdx.x;
    float acc = bo[0];
    #pragma unroll
    for (int h = 0; h < NH; h++) {
        float num = 0.f, den = 0.f;
        #pragma unroll
        for (int ci = 0; ci < NC; ci++) {
            num += pnum[((size_t)ci * N + q) * NH + h];
            den += pden[((size_t)ci * N + q) * NH + h];
        }
        acc += num / den;
    }
    out[q] = acc;
}

// ---------------------------------------------------------------------------
extern "C" void kernel_launch(void* const* d_in, const int* in_sizes, int n_in,
                              void* d_out, int out_size, void* d_ws, size_t ws_size,
                              hipStream_t stream) {
    const float* x         = (const float*)d_in[0];
    // d_in[1] = rel_pos (unused: per-query bias cancels in softmax)
    const float* rel_vel   = (const float*)d_in[2];
    const float* rel_angle = (const float*)d_in[3];
    const float* Wq        = (const float*)d_in[4];
    const float* bq        = (const float*)d_in[5];
    const float* Wk        = (const float*)d_in[6];
    const float* bk        = (const float*)d_in[7];
    const float* Wv        = (const float*)d_in[8];
    const float* bv        = (const float*)d_in[9];
    // d_in[10..13] = Wsb1,bsb1,Wsb2,bsb2 (unused)
    const float* Wmg1      = (const float*)d_in[14];
    const float* bmg1      = (const float*)d_in[15];
    const float* Wmg2      = (const float*)d_in[16];
    const float* bmg2      = (const float*)d_in[17];
    const float* Wo        = (const float*)d_in[18];
    const float* bo        = (const float*)d_in[19];
    float* out = (float*)d_out;

    // workspace layout (bf16 first, then fp32)
    __bf16* Xhi  = (__bf16*)d_ws;
    __bf16* Xlo  = Xhi + (size_t)N * IN;
    __bf16* WThi = Xlo + (size_t)N * IN;
    __bf16* WTlo = WThi + (size_t)NQK * IN;
    __bf16* Qhhi = WTlo + (size_t)NQK * IN;     // [NH][N][HD]
    __bf16* Qhlo = Qhhi + (size_t)NH * N * HD;
    __bf16* Khhi = Qhlo + (size_t)NH * N * HD;
    __bf16* Khlo = Khhi + (size_t)NH * N * HD;
    float* fp    = (float*)(Khlo + (size_t)NH * N * HD);
    float* Wvo   = fp;                          // IN*NH
    float* bvo   = Wvo + IN * NH;               // NH
    float* vpmT  = bvo + NH;                    // NH*N
    float* pnum  = vpmT + NH * N;               // NC*N*NH
    float* pden  = pnum + (size_t)NC * N * NH;  // NC*N*NH

    hipLaunchKernelGGL(prep_all, dim3(776), dim3(256), 0, stream,
                       x, Wq, Wk, Wv, bv, Wo, Xhi, Xlo, WThi, WTlo, Wvo, bvo);
    hipLaunchKernelGGL(gemm_qk, dim3(NQK / 128, N / 32), dim3(256), 0, stream,
                       Xhi, Xlo, WThi, WTlo, bq, bk, Qhhi, Qhlo, Khhi, Khlo);
    hipLaunchKernelGGL(compute_vpm, dim3(N / 32), dim3(256), 0, stream,
                       x, rel_vel, rel_angle, Wmg1, bmg1, Wmg2, bmg2, Wvo, bvo, vpmT);
    hipLaunchKernelGGL(attn_mfma, dim3(N / 128 * NH * NC), dim3(256), 0, stream,
                       Qhhi, Qhlo, Khhi, Khlo, vpmT, pnum, pden);
    hipLaunchKernelGGL(finalize, dim3(N / 64), dim3(64), 0, stream, pnum, pden, bo, out);
}

// Round 5
// 147.504 us; speedup vs baseline: 1.8764x; 1.2332x over previous
//
#include <hip/hip_runtime.h>
#include <hip/hip_bf16.h>

// Problem constants
constexpr int N    = 2048;
constexpr int IN   = 256;
constexpr int OUT  = 512;
constexpr int NH   = 8;
constexpr int HD   = 64;      // OUT / NH
constexpr int NQK  = 1024;    // Q|K concatenated columns
constexpr int NC   = 8;       // key chunks for attention
constexpr int KPB  = N / NC;  // 256 keys per chunk
constexpr int KT   = KPB / 16;// 16 key-tiles of 16

typedef __bf16    bf16x8 __attribute__((ext_vector_type(8)));
typedef __bf16    bf16x4 __attribute__((ext_vector_type(4)));
typedef _Float16  f16x8  __attribute__((ext_vector_type(8)));
typedef float     f32x4  __attribute__((ext_vector_type(4)));

#if __has_builtin(__builtin_amdgcn_exp2f)
#define EXP2(x) __builtin_amdgcn_exp2f(x)
#else
#define EXP2(x) exp2f(x)
#endif

// Q is pre-scaled by 1/sqrt(64) * log2(e) so attention uses raw exp2.
#define QSCALE (0.125f * 1.44269504088896f)

// ---------------------------------------------------------------------------
// prep_all: fused split_x (blocks 0..511) + split_w transpose (512..767) +
// prep_wvo (768..775).
// ---------------------------------------------------------------------------
__global__ __launch_bounds__(256)
void prep_all(const float* __restrict__ x,
              const float* __restrict__ Wq, const float* __restrict__ Wk,
              const float* __restrict__ Wv, const float* __restrict__ bv,
              const float* __restrict__ Wo,
              __bf16* __restrict__ Xhi, __bf16* __restrict__ Xlo,
              __bf16* __restrict__ WThi, __bf16* __restrict__ WTlo,
              float* __restrict__ Wvo, float* __restrict__ bvo) {
    __shared__ float smem[32 * 33];   // transpose tile / wo_s
    const int b = blockIdx.x;
    const int tid = threadIdx.x;

    if (b < 512) {
        // ---- split_x: bf16 hi/lo of x, same layout ----
        const size_t i4 = ((size_t)b * 256 + tid) * 4;
        const float4 v = *(const float4*)(x + i4);
        const float vv[4] = {v.x, v.y, v.z, v.w};
        bf16x4 hi, lo;
        #pragma unroll
        for (int j = 0; j < 4; j++) {
            const __bf16 h = (__bf16)vv[j];
            hi[j] = h;
            lo[j] = (__bf16)(vv[j] - (float)h);
        }
        *(bf16x4*)(Xhi + i4) = hi;
        *(bf16x4*)(Xlo + i4) = lo;
    } else if (b < 768) {
        // ---- split_w: WT[n'][k] = [Wq|Wk]^T via LDS 32x32 tile ----
        const int tb = b - 512;
        const int k0 = (tb & 7) * 32;        // k tile
        const int n0 = (tb >> 3) * 32;       // n' tile (never straddles 512)
        const float* W = (n0 < OUT) ? Wq : Wk;
        const int nc = (n0 < OUT) ? n0 : n0 - OUT;
        {
            const int row = tid >> 3;          // k within tile
            const int c4  = (tid & 7) * 4;     // n within tile
            const float4 v = *(const float4*)(W + (size_t)(k0 + row) * OUT + nc + c4);
            smem[row * 33 + c4 + 0] = v.x;
            smem[row * 33 + c4 + 1] = v.y;
            smem[row * 33 + c4 + 2] = v.z;
            smem[row * 33 + c4 + 3] = v.w;
        }
        __syncthreads();
        {
            const int nrow = tid >> 3;         // n within tile
            const int k4   = (tid & 7) * 4;    // k within tile
            bf16x4 hi, lo;
            #pragma unroll
            for (int j = 0; j < 4; j++) {
                const float v = smem[(k4 + j) * 33 + nrow];
                const __bf16 h = (__bf16)v;
                hi[j] = h;
                lo[j] = (__bf16)(v - (float)h);
            }
            const size_t off = (size_t)(n0 + nrow) * IN + k0 + k4;
            *(bf16x4*)(WThi + off) = hi;
            *(bf16x4*)(WTlo + off) = lo;
        }
    } else {
        // ---- prep_wvo ----
        float* wo_s = smem;
        wo_s[tid]       = Wo[tid];
        wo_s[tid + 256] = Wo[tid + 256];
        __syncthreads();
        const int i = (b - 768) * 32 + (tid >> 3);
        const int h = tid & 7;
        const float* wr = Wv + (size_t)i * OUT + h * HD;
        float s = 0.f;
        #pragma unroll
        for (int d = 0; d < HD; d += 4) {
            const float4 v = *(const float4*)(wr + d);
            s += v.x * wo_s[h * HD + d + 0] + v.y * wo_s[h * HD + d + 1]
               + v.z * wo_s[h * HD + d + 2] + v.w * wo_s[h * HD + d + 3];
        }
        Wvo[i * NH + h] = s;
        if (b == 768 && tid < NH) {
            float sb = 0.f;
            #pragma unroll
            for (int d = 0; d < HD; d++)
                sb += bv[tid * HD + d] * wo_s[tid * HD + d];
            bvo[tid] = sb;
        }
    }
}

// ---------------------------------------------------------------------------
// Fused Q|K GEMM via bf16x3 MFMA (fp32-quality), output rounded to fp16,
// head-major [h][m][d].  grid (NQK/128, N/32), block 256 = 4 waves.
// ---------------------------------------------------------------------------
__global__ __launch_bounds__(256)
void gemm_qk(const __bf16* __restrict__ Xhi, const __bf16* __restrict__ Xlo,
             const __bf16* __restrict__ WThi, const __bf16* __restrict__ WTlo,
             const float* __restrict__ bq, const float* __restrict__ bk,
             _Float16* __restrict__ Qh, _Float16* __restrict__ Kh) {
    __shared__ _Float16 stage[32 * 132];  // [m][n], pad 132
    const int tid  = threadIdx.x;
    const int lane = tid & 63;
    const int wave = tid >> 6;
    const int row16 = lane & 15;
    const int quad  = lane >> 4;
    const int mb = blockIdx.y * 32;
    const int nb0 = blockIdx.x * 128;
    const int nb = nb0 + wave * 32;

    const size_t ar[2] = {(size_t)(mb + row16) * IN, (size_t)(mb + 16 + row16) * IN};
    const size_t br[2] = {(size_t)(nb + row16) * IN, (size_t)(nb + 16 + row16) * IN};

    f32x4 acc[2][2] = {};
    for (int k0 = 0; k0 < IN; k0 += 32) {
        const int ko = k0 + quad * 8;
        bf16x8 ah[2], al[2], bh[2], bl[2];
        #pragma unroll
        for (int t = 0; t < 2; t++) {
            ah[t] = *(const bf16x8*)(Xhi + ar[t] + ko);
            al[t] = *(const bf16x8*)(Xlo + ar[t] + ko);
            bh[t] = *(const bf16x8*)(WThi + br[t] + ko);
            bl[t] = *(const bf16x8*)(WTlo + br[t] + ko);
        }
        #pragma unroll
        for (int mt = 0; mt < 2; mt++)
            #pragma unroll
            for (int nt = 0; nt < 2; nt++) {
                acc[mt][nt] = __builtin_amdgcn_mfma_f32_16x16x32_bf16(ah[mt], bh[nt], acc[mt][nt], 0, 0, 0);
                acc[mt][nt] = __builtin_amdgcn_mfma_f32_16x16x32_bf16(ah[mt], bl[nt], acc[mt][nt], 0, 0, 0);
                acc[mt][nt] = __builtin_amdgcn_mfma_f32_16x16x32_bf16(al[mt], bh[nt], acc[mt][nt], 0, 0, 0);
            }
    }

    // stage into LDS (C layout: col n = lane&15, row m = quad*4+r)
    const bool isQ = (nb0 < OUT);   // block-uniform (bx 0-3 Q, 4-7 K)
    const float scale = isQ ? QSCALE : 1.0f;
    #pragma unroll
    for (int mt = 0; mt < 2; mt++)
        #pragma unroll
        for (int nt = 0; nt < 2; nt++) {
            const int nl = wave * 32 + nt * 16 + row16;   // 0..127
            const int np = nb0 + nl;
            const int nq = isQ ? np : np - OUT;
            const float bias = isQ ? bq[nq] : bk[nq];
            #pragma unroll
            for (int r = 0; r < 4; r++) {
                const int ml = mt * 16 + quad * 4 + r;    // 0..31
                stage[ml * 132 + nl] = (_Float16)((acc[mt][nt][r] + bias) * scale);
            }
        }
    __syncthreads();

    // write out full lines: 64 rows (2 heads x 32 m) x 128B each
    _Float16* dst = isQ ? Qh : Kh;
    const int r2   = tid >> 2;         // 0..63
    const int cidx = tid & 3;          // 32B chunk
    const int hl   = r2 >> 5;          // head within block
    const int m    = r2 & 31;
    const int nqh  = (isQ ? nb0 : nb0 - OUT) + hl * 64;
    const int h    = nqh >> 6;
    const size_t goff = ((size_t)h * N + mb + m) * HD + cidx * 16;
    const int soff = m * 132 + hl * 64 + cidx * 16;
    *(f16x8*)(dst + goff)     = *(const f16x8*)(&stage[soff]);
    *(f16x8*)(dst + goff + 8) = *(const f16x8*)(&stage[soff + 8]);
}

// ---------------------------------------------------------------------------
// vpmT[h][k] = sigmoid(mg_mlp(k)) * ( x[k] @ Wvo[:,h] + bvo[h] )
// ---------------------------------------------------------------------------
__global__ __launch_bounds__(256)
void compute_vpm(const float* __restrict__ x, const float* __restrict__ rel_vel,
                 const float* __restrict__ rel_angle,
                 const float* __restrict__ Wmg1, const float* __restrict__ bmg1,
                 const float* __restrict__ Wmg2, const float* __restrict__ bmg2,
                 const float* __restrict__ Wvo, const float* __restrict__ bvo,
                 float* __restrict__ vpmT) {
    __shared__ float wvo_s[IN * NH];  // 8 KB
    const int tid = threadIdx.x;
    #pragma unroll
    for (int i = 0; i < 8; i++) wvo_s[tid + 256 * i] = Wvo[tid + 256 * i];
    __syncthreads();

    const int k = blockIdx.x * 32 + (tid >> 3);
    const int h = tid & 7;

    const float m0 = rel_vel[k], m1 = rel_angle[k];
    float g = bmg2[0];
    #pragma unroll
    for (int j = 0; j < HD; j++) {
        float t = m0 * Wmg1[j] + m1 * Wmg1[HD + j] + bmg1[j];
        t = fmaxf(t, 0.f);
        g += t * Wmg2[j];
    }
    const float mg = 1.f / (1.f + __expf(-g));

    const float4* xr = (const float4*)(x + (size_t)k * IN);
    float a0 = 0.f, a1 = 0.f, a2 = 0.f, a3 = 0.f;
    #pragma unroll 4
    for (int i = 0; i < IN / 4; i++) {
        const float4 v = xr[i];
        a0 += v.x * wvo_s[(i * 4 + 0) * NH + h];
        a1 += v.y * wvo_s[(i * 4 + 1) * NH + h];
        a2 += v.z * wvo_s[(i * 4 + 2) * NH + h];
        a3 += v.w * wvo_s[(i * 4 + 3) * NH + h];
    }
    vpmT[h * N + k] = mg * (a0 + a1 + a2 + a3 + bvo[h]);
}

// ---------------------------------------------------------------------------
// Attention partials, fp16 MFMA, A=K (streamed) / B=Q (64 q resident in regs).
// Wave = 64 q x 256 k for one head; block = 4 waves (consecutive q-sets);
// grid 512: h = b&7, then qg (8) x c (8).  num/den are one scalar per lane
// per q-tile (C cols = q), quad-reduced by 2 shuffles at the end.
// No LDS, no barriers.
// ---------------------------------------------------------------------------
__global__ __launch_bounds__(256)
void attn_mfma(const _Float16* __restrict__ Qh, const _Float16* __restrict__ Kh,
               const float* __restrict__ vpmT,
               float* __restrict__ pnum, float* __restrict__ pden) {
    const int b = blockIdx.x;
    const int h = b & 7;              // XCD-friendly head pin
    const int r = b >> 3;             // 0..63
    const int c = r >> 3;             // key chunk 0..7
    const int qg = r & 7;             // q-group 0..7
    const int lane = threadIdx.x & 63;
    const int wave = threadIdx.x >> 6;
    const int q0 = (qg * 4 + wave) * 64;
    const int row16 = lane & 15;
    const int quad  = lane >> 4;

    // B fragments (Q): B[n=lane&15][k=quad*8+j]; 4 q-tiles x 2 d-halves
    f16x8 Bq[4][2];
    #pragma unroll
    for (int qt = 0; qt < 4; qt++) {
        const size_t qoff = ((size_t)h * N + q0 + qt * 16 + row16) * HD + quad * 8;
        Bq[qt][0] = *(const f16x8*)(Qh + qoff);
        Bq[qt][1] = *(const f16x8*)(Qh + qoff + 32);
    }

    float num[4] = {}, den[4] = {};
    const int k0 = c * KPB;
    const size_t kbase = ((size_t)h * N + k0 + row16) * HD + quad * 8;
    const float* vp = vpmT + h * N + k0 + quad * 4;

    // register double-buffer the K tile + vpm
    f16x8 A0 = *(const f16x8*)(Kh + kbase);
    f16x8 A1 = *(const f16x8*)(Kh + kbase + 32);
    f32x4 vv = *(const f32x4*)(vp);

    #pragma unroll
    for (int t = 0; t < KT; t++) {
        const int tn = (t + 1 < KT) ? t + 1 : t;
        const size_t ka = kbase + (size_t)tn * 16 * HD;
        const f16x8 nA0 = *(const f16x8*)(Kh + ka);
        const f16x8 nA1 = *(const f16x8*)(Kh + ka + 32);
        const f32x4 nvv = *(const f32x4*)(vp + tn * 16);

        #pragma unroll
        for (int qt = 0; qt < 4; qt++) {
            f32x4 s = {0.f, 0.f, 0.f, 0.f};
            s = __builtin_amdgcn_mfma_f32_16x16x32_f16(A0, Bq[qt][0], s, 0, 0, 0);
            s = __builtin_amdgcn_mfma_f32_16x16x32_f16(A1, Bq[qt][1], s, 0, 0, 0);
            #pragma unroll
            for (int r4 = 0; r4 < 4; r4++) {
                const float e = EXP2(s[r4]);          // key k = k0+t*16+quad*4+r4
                num[qt] += e * vv[r4];
                den[qt] += e;
            }
        }
        A0 = nA0; A1 = nA1; vv = nvv;
    }

    // reduce over quads (keys are spread across quad dimension)
    #pragma unroll
    for (int qt = 0; qt < 4; qt++) {
        float n = num[qt], d = den[qt];
        n += __shfl_xor(n, 16, 64);  d += __shfl_xor(d, 16, 64);
        n += __shfl_xor(n, 32, 64);  d += __shfl_xor(d, 32, 64);
        if (quad == 0) {
            const int q = q0 + qt * 16 + row16;
            pnum[((size_t)c * NH + h) * N + q] = n;
            pden[((size_t)c * NH + h) * N + q] = d;
        }
    }
}

// ---------------------------------------------------------------------------
// finalize: out[q] = bo + sum_h (sum_c num) / (sum_c den)
// ---------------------------------------------------------------------------
__global__ __launch_bounds__(64)
void finalize(const float* __restrict__ pnum, const float* __restrict__ pden,
              const float* __restrict__ bo, float* __restrict__ out) {
    const int q = blockIdx.x * 64 + threadIdx.x;
    float acc = bo[0];
    #pragma unroll
    for (int h = 0; h < NH; h++) {
        float num = 0.f, den = 0.f;
        #pragma unroll
        for (int ci = 0; ci < NC; ci++) {
            num += pnum[((size_t)ci * NH + h) * N + q];
            den += pden[((size_t)ci * NH + h) * N + q];
        }
        acc += num / den;
    }
    out[q] = acc;
}

// ---------------------------------------------------------------------------
extern "C" void kernel_launch(void* const* d_in, const int* in_sizes, int n_in,
                              void* d_out, int out_size, void* d_ws, size_t ws_size,
                              hipStream_t stream) {
    const float* x         = (const float*)d_in[0];
    // d_in[1] = rel_pos (unused: per-query bias cancels in softmax)
    const float* rel_vel   = (const float*)d_in[2];
    const float* rel_angle = (const float*)d_in[3];
    const float* Wq        = (const float*)d_in[4];
    const float* bq        = (const float*)d_in[5];
    const float* Wk        = (const float*)d_in[6];
    const float* bk        = (const float*)d_in[7];
    const float* Wv        = (const float*)d_in[8];
    const float* bv        = (const float*)d_in[9];
    // d_in[10..13] = Wsb1,bsb1,Wsb2,bsb2 (unused)
    const float* Wmg1      = (const float*)d_in[14];
    const float* bmg1      = (const float*)d_in[15];
    const float* Wmg2      = (const float*)d_in[16];
    const float* bmg2      = (const float*)d_in[17];
    const float* Wo        = (const float*)d_in[18];
    const float* bo        = (const float*)d_in[19];
    float* out = (float*)d_out;

    // workspace layout
    __bf16* Xhi  = (__bf16*)d_ws;
    __bf16* Xlo  = Xhi + (size_t)N * IN;
    __bf16* WThi = Xlo + (size_t)N * IN;
    __bf16* WTlo = WThi + (size_t)NQK * IN;
    _Float16* Qh = (_Float16*)(WTlo + (size_t)NQK * IN);   // [NH][N][HD]
    _Float16* Kh = Qh + (size_t)NH * N * HD;
    float* fp    = (float*)(Kh + (size_t)NH * N * HD);
    float* Wvo   = fp;                          // IN*NH
    float* bvo   = Wvo + IN * NH;               // NH
    float* vpmT  = bvo + NH;                    // NH*N
    float* pnum  = vpmT + NH * N;               // NC*NH*N
    float* pden  = pnum + (size_t)NC * NH * N;  // NC*NH*N

    hipLaunchKernelGGL(prep_all, dim3(776), dim3(256), 0, stream,
                       x, Wq, Wk, Wv, bv, Wo, Xhi, Xlo, WThi, WTlo, Wvo, bvo);
    hipLaunchKernelGGL(gemm_qk, dim3(NQK / 128, N / 32), dim3(256), 0, stream,
                       Xhi, Xlo, WThi, WTlo, bq, bk, Qh, Kh);
    hipLaunchKernelGGL(compute_vpm, dim3(N / 32), dim3(256), 0, stream,
                       x, rel_vel, rel_angle, Wmg1, bmg1, Wmg2, bmg2, Wvo, bvo, vpmT);
    hipLaunchKernelGGL(attn_mfma, dim3(512), dim3(256), 0, stream,
                       Qh, Kh, vpmT, pnum, pden);
    hipLaunchKernelGGL(finalize, dim3(N / 64), dim3(64), 0, stream, pnum, pden, bo, out);
}

// Round 6
// 136.483 us; speedup vs baseline: 2.0279x; 1.0807x over previous
//
#include <hip/hip_runtime.h>
#include <hip/hip_bf16.h>

// Problem constants
constexpr int N    = 2048;
constexpr int IN   = 256;
constexpr int OUT  = 512;
constexpr int NH   = 8;
constexpr int HD   = 64;      // OUT / NH
constexpr int NQK  = 1024;    // Q|K concatenated columns
constexpr int NC   = 16;      // key chunks for attention
constexpr int KPB  = N / NC;  // 128 keys per chunk
constexpr int KT   = KPB / 16;// 8 key-tiles of 16

typedef _Float16  f16x8  __attribute__((ext_vector_type(8)));
typedef _Float16  f16x4  __attribute__((ext_vector_type(4)));
typedef float     f32x4  __attribute__((ext_vector_type(4)));

#if __has_builtin(__builtin_amdgcn_exp2f)
#define EXP2(x) __builtin_amdgcn_exp2f(x)
#else
#define EXP2(x) exp2f(x)
#endif

// Q is pre-scaled by 1/sqrt(64) * log2(e) so attention uses raw exp2.
#define QSCALE (0.125f * 1.44269504088896f)

// ---------------------------------------------------------------------------
// prep_all: blocks 0..511  : x -> fp16 X16 (same layout)
//           blocks 512..767: WT[n'][k] = fp16 transpose of [Wq|Wk]
//           blocks 768..775: Wvo[i][h] = sum_d Wv[i][h*64+d]*Wo[h*64+d], bvo
// ---------------------------------------------------------------------------
__global__ __launch_bounds__(256)
void prep_all(const float* __restrict__ x,
              const float* __restrict__ Wq, const float* __restrict__ Wk,
              const float* __restrict__ Wv, const float* __restrict__ bv,
              const float* __restrict__ Wo,
              _Float16* __restrict__ X16, _Float16* __restrict__ WT,
              float* __restrict__ Wvo, float* __restrict__ bvo) {
    __shared__ float smem[32 * 33];   // transpose tile / wo_s
    const int b = blockIdx.x;
    const int tid = threadIdx.x;

    if (b < 512) {
        // ---- x -> fp16 ----
        const size_t i4 = ((size_t)b * 256 + tid) * 4;
        const float4 v = *(const float4*)(x + i4);
        f16x4 o;
        o[0] = (_Float16)v.x; o[1] = (_Float16)v.y;
        o[2] = (_Float16)v.z; o[3] = (_Float16)v.w;
        *(f16x4*)(X16 + i4) = o;
    } else if (b < 768) {
        // ---- WT transpose via LDS 32x32 tile ----
        const int tb = b - 512;
        const int k0 = (tb & 7) * 32;        // k tile
        const int n0 = (tb >> 3) * 32;       // n' tile (never straddles 512)
        const float* W = (n0 < OUT) ? Wq : Wk;
        const int nc = (n0 < OUT) ? n0 : n0 - OUT;
        {
            const int row = tid >> 3;          // k within tile
            const int c4  = (tid & 7) * 4;     // n within tile
            const float4 v = *(const float4*)(W + (size_t)(k0 + row) * OUT + nc + c4);
            smem[row * 33 + c4 + 0] = v.x;
            smem[row * 33 + c4 + 1] = v.y;
            smem[row * 33 + c4 + 2] = v.z;
            smem[row * 33 + c4 + 3] = v.w;
        }
        __syncthreads();
        {
            const int nrow = tid >> 3;         // n within tile
            const int k4   = (tid & 7) * 4;    // k within tile
            f16x4 o;
            #pragma unroll
            for (int j = 0; j < 4; j++)
                o[j] = (_Float16)smem[(k4 + j) * 33 + nrow];
            *(f16x4*)(WT + (size_t)(n0 + nrow) * IN + k0 + k4) = o;
        }
    } else {
        // ---- prep_wvo ----
        float* wo_s = smem;
        wo_s[tid]       = Wo[tid];
        wo_s[tid + 256] = Wo[tid + 256];
        __syncthreads();
        const int i = (b - 768) * 32 + (tid >> 3);
        const int h = tid & 7;
        const float* wr = Wv + (size_t)i * OUT + h * HD;
        float s = 0.f;
        #pragma unroll
        for (int d = 0; d < HD; d += 4) {
            const float4 v = *(const float4*)(wr + d);
            s += v.x * wo_s[h * HD + d + 0] + v.y * wo_s[h * HD + d + 1]
               + v.z * wo_s[h * HD + d + 2] + v.w * wo_s[h * HD + d + 3];
        }
        Wvo[i * NH + h] = s;
        if (b == 768 && tid < NH) {
            float sb = 0.f;
            #pragma unroll
            for (int d = 0; d < HD; d++)
                sb += bv[tid * HD + d] * wo_s[tid * HD + d];
            bvo[tid] = sb;
        }
    }
}

// ---------------------------------------------------------------------------
// gemm_qk_vpm: blocks 0..511: fp16 MFMA GEMM C = X16 @ WT^T, head-major
//   fp16 output [h][m][d] (Q scaled by QSCALE, +bias).
// blocks 512..575: vpmT[h][k] = sigmoid(mg(k)) * (x[k] @ Wvo[:,h] + bvo[h])
// Both depend only on prep_all; vpm VALU waves overlap gemm MFMA waves.
// ---------------------------------------------------------------------------
__global__ __launch_bounds__(256)
void gemm_qk_vpm(const _Float16* __restrict__ X16, const _Float16* __restrict__ WT,
                 const float* __restrict__ bq, const float* __restrict__ bk,
                 _Float16* __restrict__ Qh, _Float16* __restrict__ Kh,
                 const float* __restrict__ x, const float* __restrict__ rel_vel,
                 const float* __restrict__ rel_angle,
                 const float* __restrict__ Wmg1, const float* __restrict__ bmg1,
                 const float* __restrict__ Wmg2, const float* __restrict__ bmg2,
                 const float* __restrict__ Wvo, const float* __restrict__ bvo,
                 float* __restrict__ vpmT) {
    __shared__ _Float16 stage[32 * 132];  // gemm epilogue staging
    __shared__ float wvo_s[IN * NH];      // vpm weight cache (8 KB)
    const int tid = threadIdx.x;

    if (blockIdx.x >= 512) {
        // ================= vpm branch =================
        #pragma unroll
        for (int i = 0; i < 8; i++) wvo_s[tid + 256 * i] = Wvo[tid + 256 * i];
        __syncthreads();

        const int k = (blockIdx.x - 512) * 32 + (tid >> 3);
        const int h = tid & 7;

        const float m0 = rel_vel[k], m1 = rel_angle[k];
        float g = bmg2[0];
        #pragma unroll
        for (int j = 0; j < HD; j++) {
            float t = m0 * Wmg1[j] + m1 * Wmg1[HD + j] + bmg1[j];
            t = fmaxf(t, 0.f);
            g += t * Wmg2[j];
        }
        const float mg = 1.f / (1.f + __expf(-g));

        const float4* xr = (const float4*)(x + (size_t)k * IN);
        float a0 = 0.f, a1 = 0.f, a2 = 0.f, a3 = 0.f;
        #pragma unroll 4
        for (int i = 0; i < IN / 4; i++) {
            const float4 v = xr[i];
            a0 += v.x * wvo_s[(i * 4 + 0) * NH + h];
            a1 += v.y * wvo_s[(i * 4 + 1) * NH + h];
            a2 += v.z * wvo_s[(i * 4 + 2) * NH + h];
            a3 += v.w * wvo_s[(i * 4 + 3) * NH + h];
        }
        vpmT[h * N + k] = mg * (a0 + a1 + a2 + a3 + bvo[h]);
        return;
    }

    // ================= gemm branch =================
    const int lane = tid & 63;
    const int wave = tid >> 6;
    const int row16 = lane & 15;
    const int quad  = lane >> 4;
    const int nb0 = (blockIdx.x & 7) * 128;
    const int mb  = (blockIdx.x >> 3) * 32;
    const int nb  = nb0 + wave * 32;

    const size_t ar[2] = {(size_t)(mb + row16) * IN, (size_t)(mb + 16 + row16) * IN};
    const size_t br[2] = {(size_t)(nb + row16) * IN, (size_t)(nb + 16 + row16) * IN};

    f32x4 acc[2][2] = {};
    for (int k0 = 0; k0 < IN; k0 += 32) {
        const int ko = k0 + quad * 8;
        f16x8 a[2], bf[2];
        #pragma unroll
        for (int t = 0; t < 2; t++) {
            a[t]  = *(const f16x8*)(X16 + ar[t] + ko);
            bf[t] = *(const f16x8*)(WT + br[t] + ko);
        }
        #pragma unroll
        for (int mt = 0; mt < 2; mt++)
            #pragma unroll
            for (int nt = 0; nt < 2; nt++)
                acc[mt][nt] = __builtin_amdgcn_mfma_f32_16x16x32_f16(a[mt], bf[nt], acc[mt][nt], 0, 0, 0);
    }

    // stage into LDS (C layout: col n = lane&15, row m = quad*4+r)
    const bool isQ = (nb0 < OUT);   // block-uniform
    const float scale = isQ ? QSCALE : 1.0f;
    #pragma unroll
    for (int mt = 0; mt < 2; mt++)
        #pragma unroll
        for (int nt = 0; nt < 2; nt++) {
            const int nl = wave * 32 + nt * 16 + row16;   // 0..127
            const int np = nb0 + nl;
            const int nq = isQ ? np : np - OUT;
            const float bias = isQ ? bq[nq] : bk[nq];
            #pragma unroll
            for (int r = 0; r < 4; r++) {
                const int ml = mt * 16 + quad * 4 + r;    // 0..31
                stage[ml * 132 + nl] = (_Float16)((acc[mt][nt][r] + bias) * scale);
            }
        }
    __syncthreads();

    // write out full lines: 64 rows (2 heads x 32 m) x 128B each
    _Float16* dst = isQ ? Qh : Kh;
    const int r2   = tid >> 2;         // 0..63
    const int cidx = tid & 3;          // 32B chunk
    const int hl   = r2 >> 5;          // head within block
    const int m    = r2 & 31;
    const int nqh  = (isQ ? nb0 : nb0 - OUT) + hl * 64;
    const int h    = nqh >> 6;
    const size_t goff = ((size_t)h * N + mb + m) * HD + cidx * 16;
    const int soff = m * 132 + hl * 64 + cidx * 16;
    *(f16x8*)(dst + goff)     = *(const f16x8*)(&stage[soff]);
    *(f16x8*)(dst + goff + 8) = *(const f16x8*)(&stage[soff + 8]);
}

// ---------------------------------------------------------------------------
// Attention partials, fp16 MFMA, A=K (streamed) / B=Q (64 q resident).
// Wave = 64 q x 128 k for one head; block = 4 waves; grid 1024:
// h = b&7 (XCD pin), then c (16) x qg (8).  4 blocks/CU -> 4 waves/SIMD.
// ---------------------------------------------------------------------------
__global__ __launch_bounds__(256)
void attn_mfma(const _Float16* __restrict__ Qh, const _Float16* __restrict__ Kh,
               const float* __restrict__ vpmT,
               float* __restrict__ pnum, float* __restrict__ pden) {
    const int b = blockIdx.x;
    const int h = b & 7;
    const int r = b >> 3;             // 0..127
    const int c = r >> 3;             // key chunk 0..15
    const int qg = r & 7;             // q-group 0..7
    const int lane = threadIdx.x & 63;
    const int wave = threadIdx.x >> 6;
    const int q0 = (qg * 4 + wave) * 64;
    const int row16 = lane & 15;
    const int quad  = lane >> 4;

    // B fragments (Q): B[n=lane&15][k=quad*8+j]; 4 q-tiles x 2 d-halves
    f16x8 Bq[4][2];
    #pragma unroll
    for (int qt = 0; qt < 4; qt++) {
        const size_t qoff = ((size_t)h * N + q0 + qt * 16 + row16) * HD + quad * 8;
        Bq[qt][0] = *(const f16x8*)(Qh + qoff);
        Bq[qt][1] = *(const f16x8*)(Qh + qoff + 32);
    }

    float num[4] = {}, den[4] = {};
    const int k0 = c * KPB;
    const size_t kbase = ((size_t)h * N + k0 + row16) * HD + quad * 8;
    const float* vp = vpmT + h * N + k0 + quad * 4;

    // register double-buffer the K tile + vpm
    f16x8 A0 = *(const f16x8*)(Kh + kbase);
    f16x8 A1 = *(const f16x8*)(Kh + kbase + 32);
    f32x4 vv = *(const f32x4*)(vp);

    #pragma unroll
    for (int t = 0; t < KT; t++) {
        const int tn = (t + 1 < KT) ? t + 1 : t;
        const size_t ka = kbase + (size_t)tn * 16 * HD;
        const f16x8 nA0 = *(const f16x8*)(Kh + ka);
        const f16x8 nA1 = *(const f16x8*)(Kh + ka + 32);
        const f32x4 nvv = *(const f32x4*)(vp + tn * 16);

        #pragma unroll
        for (int qt = 0; qt < 4; qt++) {
            f32x4 s = {0.f, 0.f, 0.f, 0.f};
            s = __builtin_amdgcn_mfma_f32_16x16x32_f16(A0, Bq[qt][0], s, 0, 0, 0);
            s = __builtin_amdgcn_mfma_f32_16x16x32_f16(A1, Bq[qt][1], s, 0, 0, 0);
            #pragma unroll
            for (int r4 = 0; r4 < 4; r4++) {
                const float e = EXP2(s[r4]);          // key = k0+t*16+quad*4+r4
                num[qt] += e * vv[r4];
                den[qt] += e;
            }
        }
        A0 = nA0; A1 = nA1; vv = nvv;
    }

    // reduce over quads (keys live on the quad dimension)
    #pragma unroll
    for (int qt = 0; qt < 4; qt++) {
        float n = num[qt], d = den[qt];
        n += __shfl_xor(n, 16, 64);  d += __shfl_xor(d, 16, 64);
        n += __shfl_xor(n, 32, 64);  d += __shfl_xor(d, 32, 64);
        if (quad == 0) {
            const int q = q0 + qt * 16 + row16;
            pnum[((size_t)c * NH + h) * N + q] = n;
            pden[((size_t)c * NH + h) * N + q] = d;
        }
    }
}

// ---------------------------------------------------------------------------
// finalize: out[q] = bo + sum_h (sum_c num) / (sum_c den)
// ---------------------------------------------------------------------------
__global__ __launch_bounds__(64)
void finalize(const float* __restrict__ pnum, const float* __restrict__ pden,
              const float* __restrict__ bo, float* __restrict__ out) {
    const int q = blockIdx.x * 64 + threadIdx.x;
    float acc = bo[0];
    #pragma unroll
    for (int h = 0; h < NH; h++) {
        float num = 0.f, den = 0.f;
        #pragma unroll
        for (int ci = 0; ci < NC; ci++) {
            num += pnum[((size_t)ci * NH + h) * N + q];
            den += pden[((size_t)ci * NH + h) * N + q];
        }
        acc += num / den;
    }
    out[q] = acc;
}

// ---------------------------------------------------------------------------
extern "C" void kernel_launch(void* const* d_in, const int* in_sizes, int n_in,
                              void* d_out, int out_size, void* d_ws, size_t ws_size,
                              hipStream_t stream) {
    const float* x         = (const float*)d_in[0];
    // d_in[1] = rel_pos (unused: per-query bias cancels in softmax)
    const float* rel_vel   = (const float*)d_in[2];
    const float* rel_angle = (const float*)d_in[3];
    const float* Wq        = (const float*)d_in[4];
    const float* bq        = (const float*)d_in[5];
    const float* Wk        = (const float*)d_in[6];
    const float* bk        = (const float*)d_in[7];
    const float* Wv        = (const float*)d_in[8];
    const float* bv        = (const float*)d_in[9];
    // d_in[10..13] = Wsb1,bsb1,Wsb2,bsb2 (unused)
    const float* Wmg1      = (const float*)d_in[14];
    const float* bmg1      = (const float*)d_in[15];
    const float* Wmg2      = (const float*)d_in[16];
    const float* bmg2      = (const float*)d_in[17];
    const float* Wo        = (const float*)d_in[18];
    const float* bo        = (const float*)d_in[19];
    float* out = (float*)d_out;

    // workspace layout
    _Float16* X16 = (_Float16*)d_ws;                      // N*IN
    _Float16* WT  = X16 + (size_t)N * IN;                 // NQK*IN
    _Float16* Qh  = WT + (size_t)NQK * IN;                // [NH][N][HD]
    _Float16* Kh  = Qh + (size_t)NH * N * HD;
    float* fp     = (float*)(Kh + (size_t)NH * N * HD);
    float* Wvo    = fp;                          // IN*NH
    float* bvo    = Wvo + IN * NH;               // NH
    float* vpmT   = bvo + NH;                    // NH*N
    float* pnum   = vpmT + NH * N;               // NC*NH*N
    float* pden   = pnum + (size_t)NC * NH * N;  // NC*NH*N

    hipLaunchKernelGGL(prep_all, dim3(776), dim3(256), 0, stream,
                       x, Wq, Wk, Wv, bv, Wo, X16, WT, Wvo, bvo);
    hipLaunchKernelGGL(gemm_qk_vpm, dim3(576), dim3(256), 0, stream,
                       X16, WT, bq, bk, Qh, Kh,
                       x, rel_vel, rel_angle, Wmg1, bmg1, Wmg2, bmg2, Wvo, bvo, vpmT);
    hipLaunchKernelGGL(attn_mfma, dim3(1024), dim3(256), 0, stream,
                       Qh, Kh, vpmT, pnum, pden);
    hipLaunchKernelGGL(finalize, dim3(N / 64), dim3(64), 0, stream, pnum, pden, bo, out);
}